// Round 7
// baseline (620.134 us; speedup 1.0000x reference)
//
#include <hip/hip_runtime.h>
#include <math.h>

#define L_SEQ 512
#define NB 8
#define DM 256
#define DI 512
#define NSTATE 32
#define DTR 16
#define R_ROWS 4096   // NB*L_SEQ

typedef unsigned short ushort_t;
typedef __bf16 bf16t;
typedef bf16t bf16x8 __attribute__((ext_vector_type(8)));
typedef float f32x4 __attribute__((ext_vector_type(4)));

static __device__ __forceinline__ float siluf(float x){
  return x / (1.f + __expf(-x));
}
static __device__ __forceinline__ ushort_t f2bf(float f){
  unsigned u = __float_as_uint(f);
  u += 0x7fff + ((u>>16)&1);
  return (ushort_t)(u>>16);
}
static __device__ __forceinline__ float bf2f(ushort_t h){
  return __uint_as_float(((unsigned)h)<<16);
}
// VALU cross-lane add via DPP (no DS pipe)
template<int CTRL>
static __device__ __forceinline__ float dpp_add(float v){
  int t = __builtin_amdgcn_update_dpp(0, __float_as_int(v), CTRL, 0xF, 0xF, true);
  return v + __int_as_float(t);
}

// ---------------- weight prep: fp32 -> bf16 hi/lo planes ----------------
__global__ __launch_bounds__(256) void prep_weights(
  const float* __restrict__ Wi0, const float* __restrict__ Wi1,
  const float* __restrict__ Wx0, const float* __restrict__ Wx1,
  const float* __restrict__ Wo0, const float* __restrict__ Wo1,
  const float* __restrict__ gW,  const float* __restrict__ oW,
  ushort_t* WiH0, ushort_t* WiL0, ushort_t* WiH1, ushort_t* WiL1,
  ushort_t* WxH0, ushort_t* WxL0, ushort_t* WxH1, ushort_t* WxL1,
  ushort_t* WoH,  ushort_t* WoL,  ushort_t* gH, ushort_t* gL,
  ushort_t* oH, ushort_t* oL)
{
  int i = blockIdx.x*256 + threadIdx.x;
  float v; ushort_t *ph, *pl; int oi;
  if (i < 262144){ v = Wi0[i]; ph=WiH0; pl=WiL0; oi=i; }
  else if (i < 524288){ oi=i-262144; v = Wi1[oi]; ph=WiH1; pl=WiL1; }
  else if (i < 565248){ oi=i-524288; v = Wx0[oi]; ph=WxH0; pl=WxL0; }
  else if (i < 606208){ oi=i-565248; v = Wx1[oi]; ph=WxH1; pl=WxL1; }
  else if (i < 868352){ oi=i-606208; int n=oi>>10, k=oi&1023;
                        v = (k<512)? Wo0[n*512+k] : Wo1[n*512+k-512];
                        ph=WoH; pl=WoL; }
  else if (i < 999424){ oi=i-868352; v = gW[oi]; ph=gH; pl=gL; }
  else { oi=i-999424; v = oW[oi]; ph=oH; pl=oL; }
  ushort_t h = f2bf(v);
  ph[oi] = h;
  pl[oi] = f2bf(v - bf2f(h));
}

// ---------------- LayerNorm -> bf16 hi/lo planes ----------------
__global__ __launch_bounds__(256) void ln_kernel(const float* __restrict__ x,
    const float* __restrict__ g, const float* __restrict__ b,
    ushort_t* __restrict__ xnh, ushort_t* __restrict__ xnl)
{
  int row = blockIdx.x*4 + (threadIdx.x>>6);
  int lane = threadIdx.x & 63;
  const float* xr = x + (size_t)row*DM;
  float v0 = xr[lane], v1 = xr[lane+64], v2 = xr[lane+128], v3 = xr[lane+192];
  float s = v0+v1+v2+v3;
  #pragma unroll
  for (int m=1;m<64;m<<=1) s += __shfl_xor(s, m);
  float mu = s*(1.f/DM);
  float d0=v0-mu,d1=v1-mu,d2=v2-mu,d3=v3-mu;
  float vs = d0*d0+d1*d1+d2*d2+d3*d3;
  #pragma unroll
  for (int m=1;m<64;m<<=1) vs += __shfl_xor(vs, m);
  float rstd = rsqrtf(vs*(1.f/DM)+1e-5f);
  size_t ro = (size_t)row*DM;
  #pragma unroll
  for (int j=0;j<4;j++){
    int c = lane + j*64;
    float val = (j==0?d0:j==1?d1:j==2?d2:d3)*rstd*g[c] + b[c];
    ushort_t h = f2bf(val);
    xnh[ro+c] = h;
    xnl[ro+c] = f2bf(val - bf2f(h));
  }
}

// ---------------- split-bf16 MFMA GEMM: C[M,N] = A[M,K] @ B[N,K]^T ----------------
// EPI: 0 = fp32 C; 1 = fp32 C + bias; 2 = fp32 C AND bf16 planes;
//      4 = scatter x_dbl -> dtIn[row][16] + bcI[row][64] (B,C interleaved)
template<int BM, int EPI>
__global__ __launch_bounds__(256) void gemm_mfma(
    const ushort_t* __restrict__ Ahi, const ushort_t* __restrict__ Alo, long Az,
    const ushort_t* __restrict__ Bhi, const ushort_t* __restrict__ Blo,
    int K, int N,
    float* __restrict__ C, int ldc, int Czoff,
    ushort_t* __restrict__ Phi, ushort_t* __restrict__ Plo, int ldp,
    const float* __restrict__ bias, float* __restrict__ C2)
{
  constexpr int MT = (BM==128)?4:2;
  __shared__ ushort_t Al[BM][64];
  __shared__ ushort_t Bl[128][64];
  int tid = threadIdx.x;
  int z = blockIdx.z;
  const ushort_t* Ah = Ahi + (long)z*Az;
  const ushort_t* Alw = Alo + (long)z*Az;
  float* Cz = C + (long)z*Czoff;
  int bm0 = blockIdx.y*BM, bn0 = blockIdx.x*128;

  int w = tid>>6, l = tid&63;
  int wm = w>>1, wn = w&1;
  int lr = l&15, q = l>>4;

  f32x4 acc[MT][4];
  #pragma unroll
  for (int i=0;i<MT;i++)
    #pragma unroll
    for (int j=0;j<4;j++) acc[i][j] = (f32x4){0.f,0.f,0.f,0.f};

  for (int k0=0; k0<K; k0+=32){
    #pragma unroll
    for (int p=0; p<BM/32; ++p){
      int idx = p*256 + tid;
      int row = idx>>3, c8 = idx&7;
      int kq = c8>>1, pl = c8&1;
      const ushort_t* src = (pl? Alw : Ah) + (long)(bm0+row)*K + k0 + kq*8;
      uint4 v = *(const uint4*)src;
      *(uint4*)&Al[row][(c8 ^ (row&7))<<3] = v;
    }
    #pragma unroll
    for (int p=0; p<4; ++p){
      int idx = p*256 + tid;
      int row = idx>>3, c8 = idx&7;
      int kq = c8>>1, pl = c8&1;
      int rn = bn0+row; if (rn > N-1) rn = N-1;
      const ushort_t* src = (pl? Blo : Bhi) + (long)rn*K + k0 + kq*8;
      uint4 v = *(const uint4*)src;
      *(uint4*)&Bl[row][(c8 ^ (row&7))<<3] = v;
    }
    __syncthreads();
    bf16x8 bh[4], bl[4];
    #pragma unroll
    for (int nt=0; nt<4; ++nt){
      int r = wn*64 + nt*16 + lr;
      bh[nt] = *(const bf16x8*)&Bl[r][((2*q)   ^ (r&7))<<3];
      bl[nt] = *(const bf16x8*)&Bl[r][((2*q+1) ^ (r&7))<<3];
    }
    #pragma unroll
    for (int mt=0; mt<MT; ++mt){
      int r = wm*(BM/2) + mt*16 + lr;
      bf16x8 ah = *(const bf16x8*)&Al[r][((2*q)   ^ (r&7))<<3];
      bf16x8 al = *(const bf16x8*)&Al[r][((2*q+1) ^ (r&7))<<3];
      #pragma unroll
      for (int nt=0; nt<4; ++nt){
        acc[mt][nt] = __builtin_amdgcn_mfma_f32_16x16x32_bf16(al, bh[nt], acc[mt][nt], 0,0,0);
        acc[mt][nt] = __builtin_amdgcn_mfma_f32_16x16x32_bf16(ah, bl[nt], acc[mt][nt], 0,0,0);
        acc[mt][nt] = __builtin_amdgcn_mfma_f32_16x16x32_bf16(ah, bh[nt], acc[mt][nt], 0,0,0);
      }
    }
    __syncthreads();
  }
  // epilogue: C/D frag: col = lane&15, row = (lane>>4)*4 + reg
  #pragma unroll
  for (int mt=0; mt<MT; ++mt){
    #pragma unroll
    for (int nt=0; nt<4; ++nt){
      #pragma unroll
      for (int r=0; r<4; ++r){
        int row = bm0 + wm*(BM/2) + mt*16 + q*4 + r;
        int col = bn0 + wn*64 + nt*16 + lr;
        if (col < N){
          float v = acc[mt][nt][r];
          if (EPI==4){
            if (col < DTR)      C [(long)row*16 + col] = v;
            else if (col < 48)  C2[(long)row*64 + 2*(col-DTR)] = v;
            else                C2[(long)row*64 + 2*(col-48) + 1] = v;
          } else {
            if (EPI==1) v += bias[col];
            Cz[(long)row*ldc + col] = v;
            if (EPI==2){
              ushort_t h = f2bf(v);
              (Phi + (long)z*Czoff)[(long)row*ldp + col] = h;
              (Plo + (long)z*Czoff)[(long)row*ldp + col] = f2bf(v - bf2f(h));
            }
          }
        }
      }
    }
  }
}

// ---------------- depthwise conv (both dirs) + bias + SiLU, float4 over channels ----
template<int KC>
__global__ __launch_bounds__(256) void conv_kernel(
  const float* __restrict__ xz, const float* __restrict__ w, const float* __restrict__ cb,
  float* __restrict__ xi, ushort_t* __restrict__ xih, ushort_t* __restrict__ xil)
{
  int idx = blockIdx.x*256 + threadIdx.x;   // R*DI/4 threads
  int c4 = (idx & 127) * 4;
  int t  = (idx >> 7) & (L_SEQ-1);
  int bb = idx >> 16;
  const float* base = xz + ((size_t)bb*L_SEQ)*1024 + c4;
  float4 wr[KC];
  #pragma unroll
  for (int j=0;j<KC;j++)
    wr[j] = make_float4(w[(c4+0)*KC+j], w[(c4+1)*KC+j],
                        w[(c4+2)*KC+j], w[(c4+3)*KC+j]);
  float4 bias = *(const float4*)&cb[c4];
  float4 aF = bias, aR = bias;
  #pragma unroll
  for (int j=0;j<KC;j++){
    int tf = t - (KC-1) + j;
    if (tf >= 0){
      float4 v = *(const float4*)&base[(size_t)tf*1024];
      aF.x = fmaf(wr[j].x, v.x, aF.x); aF.y = fmaf(wr[j].y, v.y, aF.y);
      aF.z = fmaf(wr[j].z, v.z, aF.z); aF.w = fmaf(wr[j].w, v.w, aF.w);
    }
    int tr = t + (KC-1) - j;
    if (tr < L_SEQ){
      float4 v = *(const float4*)&base[(size_t)tr*1024];
      aR.x = fmaf(wr[j].x, v.x, aR.x); aR.y = fmaf(wr[j].y, v.y, aR.y);
      aR.z = fmaf(wr[j].z, v.z, aR.z); aR.w = fmaf(wr[j].w, v.w, aR.w);
    }
  }
  float4 sF = make_float4(siluf(aF.x), siluf(aF.y), siluf(aF.z), siluf(aF.w));
  float4 sR = make_float4(siluf(aR.x), siluf(aR.y), siluf(aR.z), siluf(aR.w));
  const size_t RD = (size_t)R_ROWS*DI;
  size_t o = ((size_t)bb*L_SEQ + t)*DI + c4;
  *(float4*)&xi[o]    = sF;
  *(float4*)&xi[RD+o] = sR;
  ushort_t fh0=f2bf(sF.x), fh1=f2bf(sF.y), fh2=f2bf(sF.z), fh3=f2bf(sF.w);
  ushort_t rh0=f2bf(sR.x), rh1=f2bf(sR.y), rh2=f2bf(sR.z), rh3=f2bf(sR.w);
  uint2 pF = make_uint2((unsigned)fh0 | ((unsigned)fh1<<16), (unsigned)fh2 | ((unsigned)fh3<<16));
  uint2 pR = make_uint2((unsigned)rh0 | ((unsigned)rh1<<16), (unsigned)rh2 | ((unsigned)rh3<<16));
  *(uint2*)&xih[o]    = pF;
  *(uint2*)&xih[RD+o] = pR;
  uint2 lF = make_uint2((unsigned)f2bf(sF.x-bf2f(fh0)) | ((unsigned)f2bf(sF.y-bf2f(fh1))<<16),
                        (unsigned)f2bf(sF.z-bf2f(fh2)) | ((unsigned)f2bf(sF.w-bf2f(fh3))<<16));
  uint2 lR = make_uint2((unsigned)f2bf(sR.x-bf2f(rh0)) | ((unsigned)f2bf(sR.y-bf2f(rh1))<<16),
                        (unsigned)f2bf(sR.z-bf2f(rh2)) | ((unsigned)f2bf(sR.w-bf2f(rh3))<<16));
  *(uint2*)&xil[o]    = lF;
  *(uint2*)&xil[RD+o] = lR;
}

// ---------------- selective scan: DPP reduce, B/C from global, dt fused ----------------
// Block = 256 thr = 8 channels x 32 states for one (dir,b,d-block). Grid 1024.
__global__ __launch_bounds__(256) void scan_kernel(
  const float* __restrict__ dtIn,  // [2R,16]
  const float* __restrict__ bcI,   // [2R,64] (B,C) interleaved
  const float* __restrict__ xi,    // [2R,512]
  const float* __restrict__ xz,    // [R,1024] (z = cols 512..1023)
  const float* __restrict__ WdtW,  // [512,16]
  const float* __restrict__ dtb,
  const float* __restrict__ Alog,  // [512,32]
  const float* __restrict__ Dp,
  ushort_t* __restrict__ yh, ushort_t* __restrict__ yl, int col0)  // [2,R,1024]
{
  int bi = blockIdx.x;
  int dir = bi >> 9, b = (bi >> 6) & 7, d0 = (bi & 63) * 8;
  const float* dtp = dtIn + (size_t)dir*R_ROWS*16;
  const float* bcp = bcI  + (size_t)dir*R_ROWS*64;
  const float* xip = xi   + (size_t)dir*R_ROWS*DI;
  ushort_t* yoh = yh + (size_t)dir*R_ROWS*1024 + col0;
  ushort_t* yol = yl + (size_t)dir*R_ROWS*1024 + col0;
  size_t bL = (size_t)b*L_SEQ;

  __shared__ float  dtA[8][36];    // [ch][t] dt
  __shared__ float  dxA[8][36];    // [ch][t] dt*xi
  __shared__ float2 XZt[8][36];    // [ch][t] (xi,z)
  __shared__ float  YOT[8][36];    // [ch][t] y out

  int tid = threadIdx.x;
  int wv = tid>>6, l64 = tid&63;
  int ch = wv*2 + (l64>>5);        // 0..7
  int n  = l64 & 31;
  int li8 = tid>>3, c8 = tid&7;

  float Al  = -__expf(Alog[(d0+ch)*NSTATE + n]) * 1.44269504089f;
  float Dpv = Dp[d0+ch];
  const float4* wp = (const float4*)&WdtW[(d0+c8)*DTR];
  float4 w0 = wp[0], w1 = wp[1], w2 = wp[2], w3 = wp[3];
  float dtbv = dtb[d0+c8];
  bool writer = (l64==16) || (l64==48);
  float h = 0.f;

  for (int chunk=0; chunk<16; ++chunk){
    int s0 = chunk*32;
    // E: write previous chunk's y (coalesced)
    if (chunk){
      int st = s0 - 32 + li8;
      int t = dir ? (L_SEQ-1-st) : st;
      float v = YOT[c8][li8];
      ushort_t hh = f2bf(v);
      yoh[(bL + t)*1024 + d0 + c8] = hh;
      yol[(bL + t)*1024 + d0 + c8] = f2bf(v - bf2f(hh));
    }
    // B: dt = softplus(dtIn . wcol + dtb); stage dt, dt*xi, (xi,z)
    {
      int st = s0 + li8;
      int t = dir ? (L_SEQ-1-st) : st;
      size_t row = bL + t;
      const float4* dp = (const float4*)&dtp[row*16];
      float4 a0 = dp[0], a1 = dp[1], a2 = dp[2], a3 = dp[3];
      float s = dtbv;
      s = fmaf(a0.x,w0.x, fmaf(a0.y,w0.y, fmaf(a0.z,w0.z, fmaf(a0.w,w0.w, s))));
      s = fmaf(a1.x,w1.x, fmaf(a1.y,w1.y, fmaf(a1.z,w1.z, fmaf(a1.w,w1.w, s))));
      s = fmaf(a2.x,w2.x, fmaf(a2.y,w2.y, fmaf(a2.z,w2.z, fmaf(a2.w,w2.w, s))));
      s = fmaf(a3.x,w3.x, fmaf(a3.y,w3.y, fmaf(a3.z,w3.z, fmaf(a3.w,w3.w, s))));
      float dtv = fmaxf(s,0.f) + log1pf(__expf(-fabsf(s)));
      float xiv = xip[row*DI + d0 + c8];
      float zv  = xz[row*1024 + DI + d0 + c8];
      dtA[c8][li8] = dtv;
      dxA[c8][li8] = dtv * xiv;
      XZt[c8][li8] = make_float2(xiv, zv);
    }
    __syncthreads();
    // inner: 8 groups of 4 steps
    #pragma unroll
    for (int g=0; g<8; ++g){
      int t4 = g*4;
      float4 dt4 = *(const float4*)&dtA[ch][t4];
      float4 dx4 = *(const float4*)&dxA[ch][t4];
      float ys0, ys1, ys2, ys3;
      #pragma unroll
      for (int s=0; s<4; ++s){
        int st = s0 + t4 + s;
        int t = dir ? (L_SEQ-1-st) : st;
        float2 bc = *(const float2*)&bcp[(bL + t)*64 + 2*n];
        float dtv = (s==0)?dt4.x:(s==1)?dt4.y:(s==2)?dt4.z:dt4.w;
        float dxv = (s==0)?dx4.x:(s==1)?dx4.y:(s==2)?dx4.z:dx4.w;
        float dA = __builtin_amdgcn_exp2f(dtv * Al);
        h = fmaf(dA, h, dxv * bc.x);
        float yp = h * bc.y;
        yp = dpp_add<0xB1>(yp);    // quad_perm [1,0,3,2]  (xor1)
        yp = dpp_add<0x4E>(yp);    // quad_perm [2,3,0,1]  (xor2)
        yp = dpp_add<0x141>(yp);   // row_half_mirror      (xor-ish 4)
        yp = dpp_add<0x140>(yp);   // row_mirror           (xor-ish 8)
        yp = dpp_add<0x142>(yp);   // row_bcast15 -> lanes 16.. / 48.. hold 32-sum
        if (s==0) ys0=yp; else if (s==1) ys1=yp; else if (s==2) ys2=yp; else ys3=yp;
      }
      if (writer){
        float4 p0 = *(const float4*)&XZt[ch][t4];     // xi0,z0,xi1,z1
        float4 p1 = *(const float4*)&XZt[ch][t4+2];   // xi2,z2,xi3,z3
        float4 yo;
        yo.x = (ys0 + p0.x*Dpv) * siluf(p0.y);
        yo.y = (ys1 + p0.z*Dpv) * siluf(p0.w);
        yo.z = (ys2 + p1.x*Dpv) * siluf(p1.y);
        yo.w = (ys3 + p1.z*Dpv) * siluf(p1.w);
        *(float4*)&YOT[ch][t4] = yo;
      }
    }
    __syncthreads();
  }
  // final E (chunk 15)
  {
    int st = 480 + li8;
    int t = dir ? (L_SEQ-1-st) : st;
    float v = YOT[c8][li8];
    ushort_t hh = f2bf(v);
    yoh[(bL + t)*1024 + d0 + c8] = hh;
    yol[(bL + t)*1024 + d0 + c8] = f2bf(v - bf2f(hh));
  }
}

// ---------------- gate + fuse -> bf16 planes of fused ----------------
__global__ __launch_bounds__(256) void fuse_kernel(const float* __restrict__ gpre,
   const float* __restrict__ gb, const float* __restrict__ ffr,
   ushort_t* __restrict__ fush, ushort_t* __restrict__ fusl)
{
  int idx = blockIdx.x*256 + threadIdx.x;
  int r = idx >> 8, c = idx & (DM-1);
  size_t ro = (size_t)r*2*DM;
  float ffv = ffr[ro + c];
  float frv = ffr[ro + DM + c];
  float g = 1.f/(1.f+__expf(-(gpre[idx] + gb[c])));
  float v = g*ffv + (1.f-g)*frv;
  ushort_t h = f2bf(v);
  fush[idx] = h;
  fusl[idx] = f2bf(v - bf2f(h));
}

extern "C" void kernel_launch(void* const* d_in, const int* in_sizes, int n_in,
                              void* d_out, int out_size, void* d_ws, size_t ws_size,
                              hipStream_t stream)
{
  (void)in_sizes; (void)n_in; (void)out_size; (void)ws_size;
  const float* x    = (const float*)d_in[0];
  const float* ln_g = (const float*)d_in[1];
  const float* ln_b = (const float*)d_in[2];
  const float* Win[2]  = {(const float*)d_in[3],  (const float*)d_in[12]};
  const float* convw[2]= {(const float*)d_in[4],  (const float*)d_in[13]};
  const float* convb[2]= {(const float*)d_in[5],  (const float*)d_in[14]};
  const float* Wx[2]   = {(const float*)d_in[6],  (const float*)d_in[15]};
  const float* Wdt[2]  = {(const float*)d_in[7],  (const float*)d_in[16]};
  const float* dtb[2]  = {(const float*)d_in[8],  (const float*)d_in[17]};
  const float* Alog[2] = {(const float*)d_in[9],  (const float*)d_in[18]};
  const float* Dpp[2]  = {(const float*)d_in[10], (const float*)d_in[19]};
  const float* Wout[2] = {(const float*)d_in[11], (const float*)d_in[20]};
  const float* gate_W = (const float*)d_in[21];
  const float* gate_b = (const float*)d_in[22];
  const float* op_W   = (const float*)d_in[23];
  const float* op_b   = (const float*)d_in[24];
  float* out = (float*)d_out;

  char* wsb = (char*)d_ws;
  size_t off = 0;
  auto allocB = [&](size_t bytes)->char*{
    char* p = wsb + off; off += (bytes + 15) & ~size_t(15); return p; };
  const size_t R = R_ROWS;

  // fp32 buffers
  float* xzb  = (float*)allocB(R*1024*4);
  float* xi   = (float*)allocB(2*R*DI*4);
  float* dtIn = (float*)allocB(2*R*16*4);
  float* bcI  = (float*)allocB(2*R*64*4);
  float* ffr  = (float*)allocB(R*2*DM*4);
  float* gpre = (float*)allocB(R*DM*4);
  // bf16 plane buffers
  ushort_t* xnh = (ushort_t*)allocB(R*DM*2);
  ushort_t* xnl = (ushort_t*)allocB(R*DM*2);
  ushort_t* xih = (ushort_t*)allocB(2*R*DI*2);
  ushort_t* xil = (ushort_t*)allocB(2*R*DI*2);
  ushort_t* yhp = (ushort_t*)allocB(2*R*1024*2);
  ushort_t* ylp = (ushort_t*)allocB(2*R*1024*2);
  ushort_t* ffh = (ushort_t*)allocB(R*2*DM*2);
  ushort_t* ffl = (ushort_t*)allocB(R*2*DM*2);
  ushort_t* fsh = (ushort_t*)allocB(R*DM*2);
  ushort_t* fsl = (ushort_t*)allocB(R*DM*2);
  // weight planes
  ushort_t* WiH[2] = {(ushort_t*)allocB(262144*2), (ushort_t*)allocB(262144*2)};
  ushort_t* WiL[2] = {(ushort_t*)allocB(262144*2), (ushort_t*)allocB(262144*2)};
  ushort_t* WxH[2] = {(ushort_t*)allocB(40960*2),  (ushort_t*)allocB(40960*2)};
  ushort_t* WxL[2] = {(ushort_t*)allocB(40960*2),  (ushort_t*)allocB(40960*2)};
  ushort_t* WoH = (ushort_t*)allocB(262144*2);
  ushort_t* WoL = (ushort_t*)allocB(262144*2);
  ushort_t* gH  = (ushort_t*)allocB(131072*2);
  ushort_t* gL  = (ushort_t*)allocB(131072*2);
  ushort_t* oH  = (ushort_t*)allocB(65536*2);
  ushort_t* oL  = (ushort_t*)allocB(65536*2);

  prep_weights<<<4160, 256, 0, stream>>>(Win[0], Win[1], Wx[0], Wx[1],
      Wout[0], Wout[1], gate_W, op_W,
      WiH[0], WiL[0], WiH[1], WiL[1], WxH[0], WxL[0], WxH[1], WxL[1],
      WoH, WoL, gH, gL, oH, oL);

  ln_kernel<<<R/4, 256, 0, stream>>>(x, ln_g, ln_b, xnh, xnl);

  for (int m=0; m<2; ++m){
    // xz = xn @ Win^T   [4096,256] x [1024,256]^T
    gemm_mfma<128,0><<<dim3(8, 32, 1), 256, 0, stream>>>(
        xnh, xnl, 0, WiH[m], WiL[m], DM, 1024, xzb, 1024, 0,
        nullptr, nullptr, 0, nullptr, nullptr);
    if (m==0) conv_kernel<4><<<2048,256,0,stream>>>(xzb, convw[m], convb[m], xi, xih, xil);
    else      conv_kernel<8><<<2048,256,0,stream>>>(xzb, convw[m], convb[m], xi, xih, xil);
    // x_dbl = xi @ Wx^T -> dtIn + bcI   [8192,512] x [80,512]^T
    gemm_mfma<64,4><<<dim3(1, 128, 1), 256, 0, stream>>>(
        xih, xil, 0, WxH[m], WxL[m], DI, 80, dtIn, 16, 0,
        nullptr, nullptr, 0, nullptr, bcI);
    // scan (dt fused), both dirs -> y bf16 planes at col m*512
    scan_kernel<<<1024, 256, 0, stream>>>(dtIn, bcI, xi, xzb, Wdt[m], dtb[m], Alog[m], Dpp[m],
                                          yhp, ylp, m*512);
  }
  // f_dir = y[dir] @ [Wout0;Wout1]^T  (K=1024), z=dir -> ffr cols dir*256..
  gemm_mfma<128,2><<<dim3(2, 32, 2), 256, 0, stream>>>(
      yhp, ylp, (long)R*1024, WoH, WoL, 1024, 256, ffr, 2*DM, DM,
      ffh, ffl, 2*DM, nullptr, nullptr);
  // gate pre-activation: ffr @ gate_W^T  [4096,512] x [256,512]^T
  gemm_mfma<64,0><<<dim3(2, 64, 1), 256, 0, stream>>>(
      ffh, ffl, 0, gH, gL, 2*DM, DM, gpre, DM, 0,
      nullptr, nullptr, 0, nullptr, nullptr);
  fuse_kernel<<<R*DM/256, 256, 0, stream>>>(gpre, gate_b, ffr, fsh, fsl);
  // out = fused @ op_W^T + op_b
  gemm_mfma<64,1><<<dim3(2, 64, 1), 256, 0, stream>>>(
      fsh, fsl, 0, oH, oL, DM, DM, out, DM, 0,
      nullptr, nullptr, 0, op_b, nullptr);
}

// Round 8
// 580.837 us; speedup vs baseline: 1.0677x; 1.0677x over previous
//
#include <hip/hip_runtime.h>
#include <math.h>

#define L_SEQ 512
#define NB 8
#define DM 256
#define DI 512
#define NSTATE 32
#define DTR 16
#define R_ROWS 4096   // NB*L_SEQ

typedef unsigned short ushort_t;
typedef __bf16 bf16t;
typedef bf16t bf16x8 __attribute__((ext_vector_type(8)));
typedef float f32x4 __attribute__((ext_vector_type(4)));

static __device__ __forceinline__ float siluf(float x){
  return x / (1.f + __expf(-x));
}
static __device__ __forceinline__ ushort_t f2bf(float f){
  unsigned u = __float_as_uint(f);
  u += 0x7fff + ((u>>16)&1);
  return (ushort_t)(u>>16);
}
static __device__ __forceinline__ float bf2f(ushort_t h){
  return __uint_as_float(((unsigned)h)<<16);
}
// VALU cross-lane add via DPP (no DS pipe)
template<int CTRL>
static __device__ __forceinline__ float dpp_add(float v){
  int t = __builtin_amdgcn_update_dpp(0, __float_as_int(v), CTRL, 0xF, 0xF, true);
  return v + __int_as_float(t);
}

// ---------------- weight prep: fp32 -> bf16 hi/lo planes ----------------
__global__ __launch_bounds__(256) void prep_weights(
  const float* __restrict__ Wi0, const float* __restrict__ Wi1,
  const float* __restrict__ Wx0, const float* __restrict__ Wx1,
  const float* __restrict__ Wo0, const float* __restrict__ Wo1,
  const float* __restrict__ gW,  const float* __restrict__ oW,
  ushort_t* WiH0, ushort_t* WiL0, ushort_t* WiH1, ushort_t* WiL1,
  ushort_t* WxH0, ushort_t* WxL0, ushort_t* WxH1, ushort_t* WxL1,
  ushort_t* WoH,  ushort_t* WoL,  ushort_t* gH, ushort_t* gL,
  ushort_t* oH, ushort_t* oL)
{
  int i = blockIdx.x*256 + threadIdx.x;
  float v; ushort_t *ph, *pl; int oi;
  if (i < 262144){ v = Wi0[i]; ph=WiH0; pl=WiL0; oi=i; }
  else if (i < 524288){ oi=i-262144; v = Wi1[oi]; ph=WiH1; pl=WiL1; }
  else if (i < 565248){ oi=i-524288; v = Wx0[oi]; ph=WxH0; pl=WxL0; }
  else if (i < 606208){ oi=i-565248; v = Wx1[oi]; ph=WxH1; pl=WxL1; }
  else if (i < 868352){ oi=i-606208; int n=oi>>10, k=oi&1023;
                        v = (k<512)? Wo0[n*512+k] : Wo1[n*512+k-512];
                        ph=WoH; pl=WoL; }
  else if (i < 999424){ oi=i-868352; v = gW[oi]; ph=gH; pl=gL; }
  else { oi=i-999424; v = oW[oi]; ph=oH; pl=oL; }
  ushort_t h = f2bf(v);
  ph[oi] = h;
  pl[oi] = f2bf(v - bf2f(h));
}

// ---------------- LayerNorm -> bf16 hi/lo planes ----------------
__global__ __launch_bounds__(256) void ln_kernel(const float* __restrict__ x,
    const float* __restrict__ g, const float* __restrict__ b,
    ushort_t* __restrict__ xnh, ushort_t* __restrict__ xnl)
{
  int row = blockIdx.x*4 + (threadIdx.x>>6);
  int lane = threadIdx.x & 63;
  const float* xr = x + (size_t)row*DM;
  float v0 = xr[lane], v1 = xr[lane+64], v2 = xr[lane+128], v3 = xr[lane+192];
  float s = v0+v1+v2+v3;
  #pragma unroll
  for (int m=1;m<64;m<<=1) s += __shfl_xor(s, m);
  float mu = s*(1.f/DM);
  float d0=v0-mu,d1=v1-mu,d2=v2-mu,d3=v3-mu;
  float vs = d0*d0+d1*d1+d2*d2+d3*d3;
  #pragma unroll
  for (int m=1;m<64;m<<=1) vs += __shfl_xor(vs, m);
  float rstd = rsqrtf(vs*(1.f/DM)+1e-5f);
  size_t ro = (size_t)row*DM;
  #pragma unroll
  for (int j=0;j<4;j++){
    int c = lane + j*64;
    float val = (j==0?d0:j==1?d1:j==2?d2:d3)*rstd*g[c] + b[c];
    ushort_t h = f2bf(val);
    xnh[ro+c] = h;
    xnl[ro+c] = f2bf(val - bf2f(h));
  }
}

// ---------------- split-bf16 MFMA GEMM: C[M,N] = A[M,K] @ B[N,K]^T ----------------
// EPI: 0 = fp32 C; 1 = fp32 C + bias; 2 = fp32 C AND bf16 planes;
//      4 = scatter x_dbl -> dtIn[row][16] + bcI[row][64] (B,C interleaved)
template<int BM, int EPI>
__global__ __launch_bounds__(256) void gemm_mfma(
    const ushort_t* __restrict__ Ahi, const ushort_t* __restrict__ Alo, long Az,
    const ushort_t* __restrict__ Bhi, const ushort_t* __restrict__ Blo,
    int K, int N,
    float* __restrict__ C, int ldc, int Czoff,
    ushort_t* __restrict__ Phi, ushort_t* __restrict__ Plo, int ldp,
    const float* __restrict__ bias, float* __restrict__ C2)
{
  constexpr int MT = (BM==128)?4:2;
  __shared__ ushort_t Al[BM][64];
  __shared__ ushort_t Bl[128][64];
  int tid = threadIdx.x;
  int z = blockIdx.z;
  const ushort_t* Ah = Ahi + (long)z*Az;
  const ushort_t* Alw = Alo + (long)z*Az;
  float* Cz = C + (long)z*Czoff;
  int bm0 = blockIdx.y*BM, bn0 = blockIdx.x*128;

  int w = tid>>6, l = tid&63;
  int wm = w>>1, wn = w&1;
  int lr = l&15, q = l>>4;

  f32x4 acc[MT][4];
  #pragma unroll
  for (int i=0;i<MT;i++)
    #pragma unroll
    for (int j=0;j<4;j++) acc[i][j] = (f32x4){0.f,0.f,0.f,0.f};

  for (int k0=0; k0<K; k0+=32){
    #pragma unroll
    for (int p=0; p<BM/32; ++p){
      int idx = p*256 + tid;
      int row = idx>>3, c8 = idx&7;
      int kq = c8>>1, pl = c8&1;
      const ushort_t* src = (pl? Alw : Ah) + (long)(bm0+row)*K + k0 + kq*8;
      uint4 v = *(const uint4*)src;
      *(uint4*)&Al[row][(c8 ^ (row&7))<<3] = v;
    }
    #pragma unroll
    for (int p=0; p<4; ++p){
      int idx = p*256 + tid;
      int row = idx>>3, c8 = idx&7;
      int kq = c8>>1, pl = c8&1;
      int rn = bn0+row; if (rn > N-1) rn = N-1;
      const ushort_t* src = (pl? Blo : Bhi) + (long)rn*K + k0 + kq*8;
      uint4 v = *(const uint4*)src;
      *(uint4*)&Bl[row][(c8 ^ (row&7))<<3] = v;
    }
    __syncthreads();
    bf16x8 bh[4], bl[4];
    #pragma unroll
    for (int nt=0; nt<4; ++nt){
      int r = wn*64 + nt*16 + lr;
      bh[nt] = *(const bf16x8*)&Bl[r][((2*q)   ^ (r&7))<<3];
      bl[nt] = *(const bf16x8*)&Bl[r][((2*q+1) ^ (r&7))<<3];
    }
    #pragma unroll
    for (int mt=0; mt<MT; ++mt){
      int r = wm*(BM/2) + mt*16 + lr;
      bf16x8 ah = *(const bf16x8*)&Al[r][((2*q)   ^ (r&7))<<3];
      bf16x8 al = *(const bf16x8*)&Al[r][((2*q+1) ^ (r&7))<<3];
      #pragma unroll
      for (int nt=0; nt<4; ++nt){
        acc[mt][nt] = __builtin_amdgcn_mfma_f32_16x16x32_bf16(al, bh[nt], acc[mt][nt], 0,0,0);
        acc[mt][nt] = __builtin_amdgcn_mfma_f32_16x16x32_bf16(ah, bl[nt], acc[mt][nt], 0,0,0);
        acc[mt][nt] = __builtin_amdgcn_mfma_f32_16x16x32_bf16(ah, bh[nt], acc[mt][nt], 0,0,0);
      }
    }
    __syncthreads();
  }
  // epilogue: C/D frag: col = lane&15, row = (lane>>4)*4 + reg
  #pragma unroll
  for (int mt=0; mt<MT; ++mt){
    #pragma unroll
    for (int nt=0; nt<4; ++nt){
      #pragma unroll
      for (int r=0; r<4; ++r){
        int row = bm0 + wm*(BM/2) + mt*16 + q*4 + r;
        int col = bn0 + wn*64 + nt*16 + lr;
        if (col < N){
          float v = acc[mt][nt][r];
          if (EPI==4){
            if (col < DTR)      C [(long)row*16 + col] = v;
            else if (col < 48)  C2[(long)row*64 + 2*(col-DTR)] = v;
            else                C2[(long)row*64 + 2*(col-48) + 1] = v;
          } else {
            if (EPI==1) v += bias[col];
            Cz[(long)row*ldc + col] = v;
            if (EPI==2){
              ushort_t h = f2bf(v);
              (Phi + (long)z*Czoff)[(long)row*ldp + col] = h;
              (Plo + (long)z*Czoff)[(long)row*ldp + col] = f2bf(v - bf2f(h));
            }
          }
        }
      }
    }
  }
}

// ---------------- depthwise conv (both dirs) + bias + SiLU -> bf16 hi/lo planes ----
template<int KC>
__global__ __launch_bounds__(256) void conv_kernel(
  const float* __restrict__ xz, const float* __restrict__ w, const float* __restrict__ cb,
  ushort_t* __restrict__ xih, ushort_t* __restrict__ xil)
{
  int idx = blockIdx.x*256 + threadIdx.x;   // R*DI/4 threads
  int c4 = (idx & 127) * 4;
  int t  = (idx >> 7) & (L_SEQ-1);
  int bb = idx >> 16;
  const float* base = xz + ((size_t)bb*L_SEQ)*1024 + c4;
  float4 wr[KC];
  #pragma unroll
  for (int j=0;j<KC;j++)
    wr[j] = make_float4(w[(c4+0)*KC+j], w[(c4+1)*KC+j],
                        w[(c4+2)*KC+j], w[(c4+3)*KC+j]);
  float4 bias = *(const float4*)&cb[c4];
  float4 aF = bias, aR = bias;
  #pragma unroll
  for (int j=0;j<KC;j++){
    int tf = t - (KC-1) + j;
    if (tf >= 0){
      float4 v = *(const float4*)&base[(size_t)tf*1024];
      aF.x = fmaf(wr[j].x, v.x, aF.x); aF.y = fmaf(wr[j].y, v.y, aF.y);
      aF.z = fmaf(wr[j].z, v.z, aF.z); aF.w = fmaf(wr[j].w, v.w, aF.w);
    }
    int tr = t + (KC-1) - j;
    if (tr < L_SEQ){
      float4 v = *(const float4*)&base[(size_t)tr*1024];
      aR.x = fmaf(wr[j].x, v.x, aR.x); aR.y = fmaf(wr[j].y, v.y, aR.y);
      aR.z = fmaf(wr[j].z, v.z, aR.z); aR.w = fmaf(wr[j].w, v.w, aR.w);
    }
  }
  float4 sF = make_float4(siluf(aF.x), siluf(aF.y), siluf(aF.z), siluf(aF.w));
  float4 sR = make_float4(siluf(aR.x), siluf(aR.y), siluf(aR.z), siluf(aR.w));
  const size_t RD = (size_t)R_ROWS*DI;
  size_t o = ((size_t)bb*L_SEQ + t)*DI + c4;
  ushort_t fh0=f2bf(sF.x), fh1=f2bf(sF.y), fh2=f2bf(sF.z), fh3=f2bf(sF.w);
  ushort_t rh0=f2bf(sR.x), rh1=f2bf(sR.y), rh2=f2bf(sR.z), rh3=f2bf(sR.w);
  uint2 pF = make_uint2((unsigned)fh0 | ((unsigned)fh1<<16), (unsigned)fh2 | ((unsigned)fh3<<16));
  uint2 pR = make_uint2((unsigned)rh0 | ((unsigned)rh1<<16), (unsigned)rh2 | ((unsigned)rh3<<16));
  *(uint2*)&xih[o]    = pF;
  *(uint2*)&xih[RD+o] = pR;
  uint2 lF = make_uint2((unsigned)f2bf(sF.x-bf2f(fh0)) | ((unsigned)f2bf(sF.y-bf2f(fh1))<<16),
                        (unsigned)f2bf(sF.z-bf2f(fh2)) | ((unsigned)f2bf(sF.w-bf2f(fh3))<<16));
  uint2 lR = make_uint2((unsigned)f2bf(sR.x-bf2f(rh0)) | ((unsigned)f2bf(sR.y-bf2f(rh1))<<16),
                        (unsigned)f2bf(sR.z-bf2f(rh2)) | ((unsigned)f2bf(sR.w-bf2f(rh3))<<16));
  *(uint2*)&xil[o]    = lF;
  *(uint2*)&xil[RD+o] = lR;
}

// ---------------- selective scan: ALL (m,dir) in one launch, ILP-batched DPP reduce ----
// Grid 2048 = m(2) x dir(2) x b(8) x dblk(64); block = 256 thr = 8 ch x 32 states.
// 8 blocks/CU -> 8 waves/SIMD for hazard/latency hiding.
__global__ __launch_bounds__(256, 8) void scan_kernel(
  const float* __restrict__ dtIn,  // [2][2R][16]
  const float* __restrict__ bcI,   // [2][2R][64] (B,C) interleaved
  const ushort_t* __restrict__ xih,// [2][2R][512]
  const ushort_t* __restrict__ xil,
  const float* __restrict__ xz,    // [2][R][1024] (z = cols 512..1023)
  const float* __restrict__ Wdt0, const float* __restrict__ Wdt1,   // [512,16]
  const float* __restrict__ dtb0, const float* __restrict__ dtb1,
  const float* __restrict__ Alog0,const float* __restrict__ Alog1,  // [512,32]
  const float* __restrict__ Dp0,  const float* __restrict__ Dp1,
  ushort_t* __restrict__ yh, ushort_t* __restrict__ yl)  // [2(dir)][R][1024], col m*512
{
  int bi = blockIdx.x;
  int m = bi >> 10, dir = (bi >> 9) & 1, b = (bi >> 6) & 7, d0 = (bi & 63) * 8;
  const float* WdtW = m ? Wdt1 : Wdt0;
  const float* dtbp = m ? dtb1 : dtb0;
  const float* Alog = m ? Alog1 : Alog0;
  const float* Dp   = m ? Dp1   : Dp0;
  size_t md = (size_t)m*2 + dir;
  const float*    dtp = dtIn + md*R_ROWS*16;
  const float*    bcp = bcI  + md*R_ROWS*64;
  const ushort_t* xhp = xih  + md*R_ROWS*DI;
  const ushort_t* xlp = xil  + md*R_ROWS*DI;
  const float*    zp  = xz   + (size_t)m*R_ROWS*1024;
  ushort_t* yoh = yh + (size_t)dir*R_ROWS*1024 + m*512;
  ushort_t* yol = yl + (size_t)dir*R_ROWS*1024 + m*512;
  size_t bL = (size_t)b*L_SEQ;

  __shared__ float  dtA[8][36];    // [ch][t] dt
  __shared__ float  dxA[8][36];    // [ch][t] dt*xi
  __shared__ float2 XZt[8][36];    // [ch][t] (xi,z)
  __shared__ float  YOT[8][36];    // [ch][t] y out

  int tid = threadIdx.x;
  int wv = tid>>6, l64 = tid&63;
  int ch = wv*2 + (l64>>5);        // 0..7
  int n  = l64 & 31;
  int li8 = tid>>3, c8 = tid&7;

  float Al  = -__expf(Alog[(d0+ch)*NSTATE + n]) * 1.44269504089f;
  float Dpv = Dp[d0+ch];
  const float4* wp = (const float4*)&WdtW[(d0+c8)*DTR];
  float4 w0 = wp[0], w1 = wp[1], w2 = wp[2], w3 = wp[3];
  float dtbv = dtbp[d0+c8];
  bool writer = (l64==16) || (l64==48);
  float h = 0.f;

  for (int chunk=0; chunk<16; ++chunk){
    int s0 = chunk*32;
    // E: write previous chunk's y (coalesced)
    if (chunk){
      int st = s0 - 32 + li8;
      int t = dir ? (L_SEQ-1-st) : st;
      float v = YOT[c8][li8];
      ushort_t hh = f2bf(v);
      yoh[(bL + t)*1024 + d0 + c8] = hh;
      yol[(bL + t)*1024 + d0 + c8] = f2bf(v - bf2f(hh));
    }
    // B: dt = softplus(dtIn . wcol + dtb); stage dt, dt*xi, (xi,z)
    {
      int st = s0 + li8;
      int t = dir ? (L_SEQ-1-st) : st;
      size_t row = bL + t;
      const float4* dp = (const float4*)&dtp[row*16];
      float4 a0 = dp[0], a1 = dp[1], a2 = dp[2], a3 = dp[3];
      float s = dtbv;
      s = fmaf(a0.x,w0.x, fmaf(a0.y,w0.y, fmaf(a0.z,w0.z, fmaf(a0.w,w0.w, s))));
      s = fmaf(a1.x,w1.x, fmaf(a1.y,w1.y, fmaf(a1.z,w1.z, fmaf(a1.w,w1.w, s))));
      s = fmaf(a2.x,w2.x, fmaf(a2.y,w2.y, fmaf(a2.z,w2.z, fmaf(a2.w,w2.w, s))));
      s = fmaf(a3.x,w3.x, fmaf(a3.y,w3.y, fmaf(a3.z,w3.z, fmaf(a3.w,w3.w, s))));
      float dtv = fmaxf(s,0.f) + log1pf(__expf(-fabsf(s)));
      float xiv = bf2f(xhp[row*DI + d0 + c8]) + bf2f(xlp[row*DI + d0 + c8]);
      float zv  = zp[row*1024 + DI + d0 + c8];
      dtA[c8][li8] = dtv;
      dxA[c8][li8] = dtv * xiv;
      XZt[c8][li8] = make_float2(xiv, zv);
    }
    __syncthreads();
    // inner: 8 groups of 4 steps; reduce batched for ILP
    #pragma unroll
    for (int g=0; g<8; ++g){
      int t4 = g*4;
      float4 dt4 = *(const float4*)&dtA[ch][t4];
      float4 dx4 = *(const float4*)&dxA[ch][t4];
      // prefetch B/C for 4 steps (independent VMEM)
      float2 bc0, bc1, bc2, bc3;
      {
        int st = s0 + t4;
        int t0 = dir ? (L_SEQ-1-st)   : st;
        int t1 = dir ? (L_SEQ-1-st-1) : st+1;
        int t2 = dir ? (L_SEQ-1-st-2) : st+2;
        int t3 = dir ? (L_SEQ-1-st-3) : st+3;
        bc0 = *(const float2*)&bcp[(bL + t0)*64 + 2*n];
        bc1 = *(const float2*)&bcp[(bL + t1)*64 + 2*n];
        bc2 = *(const float2*)&bcp[(bL + t2)*64 + 2*n];
        bc3 = *(const float2*)&bcp[(bL + t3)*64 + 2*n];
      }
      // serial h-chain (cheap), collect yp
      float yp0, yp1, yp2, yp3;
      h = fmaf(__builtin_amdgcn_exp2f(dt4.x * Al), h, dx4.x * bc0.x); yp0 = h * bc0.y;
      h = fmaf(__builtin_amdgcn_exp2f(dt4.y * Al), h, dx4.y * bc1.x); yp1 = h * bc1.y;
      h = fmaf(__builtin_amdgcn_exp2f(dt4.z * Al), h, dx4.z * bc2.x); yp2 = h * bc2.y;
      h = fmaf(__builtin_amdgcn_exp2f(dt4.w * Al), h, dx4.w * bc3.x); yp3 = h * bc3.y;
      // interleaved 5-level reduce: 4 independent chains per level (hazard-hiding ILP)
      yp0 = dpp_add<0xB1>(yp0);  yp1 = dpp_add<0xB1>(yp1);
      yp2 = dpp_add<0xB1>(yp2);  yp3 = dpp_add<0xB1>(yp3);
      yp0 = dpp_add<0x4E>(yp0);  yp1 = dpp_add<0x4E>(yp1);
      yp2 = dpp_add<0x4E>(yp2);  yp3 = dpp_add<0x4E>(yp3);
      yp0 = dpp_add<0x141>(yp0); yp1 = dpp_add<0x141>(yp1);
      yp2 = dpp_add<0x141>(yp2); yp3 = dpp_add<0x141>(yp3);
      yp0 = dpp_add<0x140>(yp0); yp1 = dpp_add<0x140>(yp1);
      yp2 = dpp_add<0x140>(yp2); yp3 = dpp_add<0x140>(yp3);
      yp0 = dpp_add<0x142>(yp0); yp1 = dpp_add<0x142>(yp1);
      yp2 = dpp_add<0x142>(yp2); yp3 = dpp_add<0x142>(yp3);
      if (writer){
        float4 p0 = *(const float4*)&XZt[ch][t4];     // xi0,z0,xi1,z1
        float4 p1 = *(const float4*)&XZt[ch][t4+2];   // xi2,z2,xi3,z3
        float4 yo;
        yo.x = (yp0 + p0.x*Dpv) * siluf(p0.y);
        yo.y = (yp1 + p0.z*Dpv) * siluf(p0.w);
        yo.z = (yp2 + p1.x*Dpv) * siluf(p1.y);
        yo.w = (yp3 + p1.z*Dpv) * siluf(p1.w);
        *(float4*)&YOT[ch][t4] = yo;
      }
    }
    __syncthreads();
  }
  // final E (chunk 15)
  {
    int st = 480 + li8;
    int t = dir ? (L_SEQ-1-st) : st;
    float v = YOT[c8][li8];
    ushort_t hh = f2bf(v);
    yoh[(bL + t)*1024 + d0 + c8] = hh;
    yol[(bL + t)*1024 + d0 + c8] = f2bf(v - bf2f(hh));
  }
}

// ---------------- gate + fuse -> bf16 planes of fused ----------------
__global__ __launch_bounds__(256) void fuse_kernel(const float* __restrict__ gpre,
   const float* __restrict__ gb, const float* __restrict__ ffr,
   ushort_t* __restrict__ fush, ushort_t* __restrict__ fusl)
{
  int idx = blockIdx.x*256 + threadIdx.x;
  int r = idx >> 8, c = idx & (DM-1);
  size_t ro = (size_t)r*2*DM;
  float ffv = ffr[ro + c];
  float frv = ffr[ro + DM + c];
  float g = 1.f/(1.f+__expf(-(gpre[idx] + gb[c])));
  float v = g*ffv + (1.f-g)*frv;
  ushort_t h = f2bf(v);
  fush[idx] = h;
  fusl[idx] = f2bf(v - bf2f(h));
}

extern "C" void kernel_launch(void* const* d_in, const int* in_sizes, int n_in,
                              void* d_out, int out_size, void* d_ws, size_t ws_size,
                              hipStream_t stream)
{
  (void)in_sizes; (void)n_in; (void)out_size; (void)ws_size;
  const float* x    = (const float*)d_in[0];
  const float* ln_g = (const float*)d_in[1];
  const float* ln_b = (const float*)d_in[2];
  const float* Win[2]  = {(const float*)d_in[3],  (const float*)d_in[12]};
  const float* convw[2]= {(const float*)d_in[4],  (const float*)d_in[13]};
  const float* convb[2]= {(const float*)d_in[5],  (const float*)d_in[14]};
  const float* Wx[2]   = {(const float*)d_in[6],  (const float*)d_in[15]};
  const float* Wdt[2]  = {(const float*)d_in[7],  (const float*)d_in[16]};
  const float* dtb[2]  = {(const float*)d_in[8],  (const float*)d_in[17]};
  const float* Alog[2] = {(const float*)d_in[9],  (const float*)d_in[18]};
  const float* Dpp[2]  = {(const float*)d_in[10], (const float*)d_in[19]};
  const float* Wout[2] = {(const float*)d_in[11], (const float*)d_in[20]};
  const float* gate_W = (const float*)d_in[21];
  const float* gate_b = (const float*)d_in[22];
  const float* op_W   = (const float*)d_in[23];
  const float* op_b   = (const float*)d_in[24];
  float* out = (float*)d_out;

  char* wsb = (char*)d_ws;
  size_t off = 0;
  auto allocB = [&](size_t bytes)->char*{
    char* p = wsb + off; off += (bytes + 255) & ~size_t(255); return p; };
  const size_t R = R_ROWS;

  // persistent region
  float* xzb  = (float*)allocB(2*R*1024*4);        // [m][R][1024]
  float* dtIn = (float*)allocB(2*2*R*16*4);        // [m][dir R][16]
  float* bcI  = (float*)allocB(2*2*R*64*4);        // [m][dir R][64]
  ushort_t* xnh = (ushort_t*)allocB(R*DM*2);
  ushort_t* xnl = (ushort_t*)allocB(R*DM*2);
  ushort_t* yhp = (ushort_t*)allocB(2*R*1024*2);   // [dir][R][1024], col m*512
  ushort_t* ylp = (ushort_t*)allocB(2*R*1024*2);
  // weight planes
  ushort_t* WiH[2] = {(ushort_t*)allocB(262144*2), (ushort_t*)allocB(262144*2)};
  ushort_t* WiL[2] = {(ushort_t*)allocB(262144*2), (ushort_t*)allocB(262144*2)};
  ushort_t* WxH[2] = {(ushort_t*)allocB(40960*2),  (ushort_t*)allocB(40960*2)};
  ushort_t* WxL[2] = {(ushort_t*)allocB(40960*2),  (ushort_t*)allocB(40960*2)};
  ushort_t* WoH = (ushort_t*)allocB(262144*2);
  ushort_t* WoL = (ushort_t*)allocB(262144*2);
  ushort_t* gH  = (ushort_t*)allocB(131072*2);
  ushort_t* gL  = (ushort_t*)allocB(131072*2);
  ushort_t* oH  = (ushort_t*)allocB(65536*2);
  ushort_t* oL  = (ushort_t*)allocB(65536*2);

  // union region: phase1 = xih/xil (live through scan); phase2 = post-scan buffers
  size_t uo = off;
  ushort_t* xih = (ushort_t*)allocB(2*2*R*DI*2);   // [m][dir R][512]
  ushort_t* xil = (ushort_t*)allocB(2*2*R*DI*2);
  // phase2 overlays (written only after scan completes)
  char* p2 = wsb + uo;
  float* ffr  = (float*)p2;              p2 += (size_t)R*2*DM*4;
  float* gpre = (float*)p2;              p2 += (size_t)R*DM*4;
  ushort_t* ffh = (ushort_t*)p2;         p2 += (size_t)R*2*DM*2;
  ushort_t* ffl = (ushort_t*)p2;         p2 += (size_t)R*2*DM*2;
  ushort_t* fsh = (ushort_t*)p2;         p2 += (size_t)R*DM*2;
  ushort_t* fsl = (ushort_t*)p2;         p2 += (size_t)R*DM*2;

  prep_weights<<<4160, 256, 0, stream>>>(Win[0], Win[1], Wx[0], Wx[1],
      Wout[0], Wout[1], gate_W, op_W,
      WiH[0], WiL[0], WiH[1], WiL[1], WxH[0], WxL[0], WxH[1], WxL[1],
      WoH, WoL, gH, gL, oH, oL);

  ln_kernel<<<R/4, 256, 0, stream>>>(x, ln_g, ln_b, xnh, xnl);

  for (int m=0; m<2; ++m){
    float* xzm = xzb + (size_t)m*R*1024;
    ushort_t* xihm = xih + (size_t)m*2*R*DI;
    ushort_t* xilm = xil + (size_t)m*2*R*DI;
    // xz = xn @ Win^T   [4096,256] x [1024,256]^T
    gemm_mfma<128,0><<<dim3(8, 32, 1), 256, 0, stream>>>(
        xnh, xnl, 0, WiH[m], WiL[m], DM, 1024, xzm, 1024, 0,
        nullptr, nullptr, 0, nullptr, nullptr);
    if (m==0) conv_kernel<4><<<2048,256,0,stream>>>(xzm, convw[m], convb[m], xihm, xilm);
    else      conv_kernel<8><<<2048,256,0,stream>>>(xzm, convw[m], convb[m], xihm, xilm);
    // x_dbl = xi @ Wx^T -> dtIn + bcI   [8192,512] x [80,512]^T
    gemm_mfma<64,4><<<dim3(1, 128, 1), 256, 0, stream>>>(
        xihm, xilm, 0, WxH[m], WxL[m], DI, 80, dtIn + (size_t)m*2*R*16, 16, 0,
        nullptr, nullptr, 0, nullptr, bcI + (size_t)m*2*R*64);
  }
  // ONE merged scan: all (m,dir) -> 2048 blocks = 8 blocks/CU
  scan_kernel<<<2048, 256, 0, stream>>>(dtIn, bcI, xih, xil, xzb,
      Wdt[0], Wdt[1], dtb[0], dtb[1], Alog[0], Alog[1], Dpp[0], Dpp[1],
      yhp, ylp);
  // f_dir = y[dir] @ [Wout0;Wout1]^T  (K=1024), z=dir -> ffr cols dir*256..
  gemm_mfma<128,2><<<dim3(2, 32, 2), 256, 0, stream>>>(
      yhp, ylp, (long)R*1024, WoH, WoL, 1024, 256, ffr, 2*DM, DM,
      ffh, ffl, 2*DM, nullptr, nullptr);
  // gate pre-activation: ffr @ gate_W^T  [4096,512] x [256,512]^T
  gemm_mfma<64,0><<<dim3(2, 64, 1), 256, 0, stream>>>(
      ffh, ffl, 0, gH, gL, 2*DM, DM, gpre, DM, 0,
      nullptr, nullptr, 0, nullptr, nullptr);
  fuse_kernel<<<R*DM/256, 256, 0, stream>>>(gpre, gate_b, ffr, fsh, fsl);
  // out = fused @ op_W^T + op_b
  gemm_mfma<64,1><<<dim3(2, 64, 1), 256, 0, stream>>>(
      fsh, fsl, 0, oH, oL, DM, DM, out, DM, 0,
      nullptr, nullptr, 0, op_b, nullptr);
}

// Round 9
// 538.936 us; speedup vs baseline: 1.1507x; 1.0777x over previous
//
#include <hip/hip_runtime.h>
#include <math.h>

#define L_SEQ 512
#define NB 8
#define DM 256
#define DI 512
#define NSTATE 32
#define DTR 16
#define R_ROWS 4096   // NB*L_SEQ

typedef unsigned short ushort_t;
typedef __bf16 bf16t;
typedef bf16t bf16x8 __attribute__((ext_vector_type(8)));
typedef float f32x4 __attribute__((ext_vector_type(4)));

static __device__ __forceinline__ float siluf(float x){
  return x / (1.f + __expf(-x));
}
static __device__ __forceinline__ ushort_t f2bf(float f){
  unsigned u = __float_as_uint(f);
  u += 0x7fff + ((u>>16)&1);
  return (ushort_t)(u>>16);
}
static __device__ __forceinline__ float bf2f(ushort_t h){
  return __uint_as_float(((unsigned)h)<<16);
}
// VALU cross-lane add via DPP (no DS pipe)
template<int CTRL>
static __device__ __forceinline__ float dpp_add(float v){
  int t = __builtin_amdgcn_update_dpp(0, __float_as_int(v), CTRL, 0xF, 0xF, true);
  return v + __int_as_float(t);
}

// ---------------- weight prep: fp32 -> bf16 hi/lo planes ----------------
__global__ __launch_bounds__(256) void prep_weights(
  const float* __restrict__ Wi0, const float* __restrict__ Wi1,
  const float* __restrict__ Wx0, const float* __restrict__ Wx1,
  const float* __restrict__ Wo0, const float* __restrict__ Wo1,
  const float* __restrict__ gW,  const float* __restrict__ oW,
  ushort_t* WiH0, ushort_t* WiL0, ushort_t* WiH1, ushort_t* WiL1,
  ushort_t* WxH0, ushort_t* WxL0, ushort_t* WxH1, ushort_t* WxL1,
  ushort_t* WoH,  ushort_t* WoL,  ushort_t* gH, ushort_t* gL,
  ushort_t* oH, ushort_t* oL)
{
  int i = blockIdx.x*256 + threadIdx.x;
  float v; ushort_t *ph, *pl; int oi;
  if (i < 262144){ v = Wi0[i]; ph=WiH0; pl=WiL0; oi=i; }
  else if (i < 524288){ oi=i-262144; v = Wi1[oi]; ph=WiH1; pl=WiL1; }
  else if (i < 565248){ oi=i-524288; v = Wx0[oi]; ph=WxH0; pl=WxL0; }
  else if (i < 606208){ oi=i-565248; v = Wx1[oi]; ph=WxH1; pl=WxL1; }
  else if (i < 868352){ oi=i-606208; int n=oi>>10, k=oi&1023;
                        v = (k<512)? Wo0[n*512+k] : Wo1[n*512+k-512];
                        ph=WoH; pl=WoL; }
  else if (i < 999424){ oi=i-868352; v = gW[oi]; ph=gH; pl=gL; }
  else { oi=i-999424; v = oW[oi]; ph=oH; pl=oL; }
  ushort_t h = f2bf(v);
  ph[oi] = h;
  pl[oi] = f2bf(v - bf2f(h));
}

// ---------------- LayerNorm -> bf16 hi/lo planes ----------------
__global__ __launch_bounds__(256) void ln_kernel(const float* __restrict__ x,
    const float* __restrict__ g, const float* __restrict__ b,
    ushort_t* __restrict__ xnh, ushort_t* __restrict__ xnl)
{
  int row = blockIdx.x*4 + (threadIdx.x>>6);
  int lane = threadIdx.x & 63;
  const float* xr = x + (size_t)row*DM;
  float v0 = xr[lane], v1 = xr[lane+64], v2 = xr[lane+128], v3 = xr[lane+192];
  float s = v0+v1+v2+v3;
  #pragma unroll
  for (int m=1;m<64;m<<=1) s += __shfl_xor(s, m);
  float mu = s*(1.f/DM);
  float d0=v0-mu,d1=v1-mu,d2=v2-mu,d3=v3-mu;
  float vs = d0*d0+d1*d1+d2*d2+d3*d3;
  #pragma unroll
  for (int m=1;m<64;m<<=1) vs += __shfl_xor(vs, m);
  float rstd = rsqrtf(vs*(1.f/DM)+1e-5f);
  size_t ro = (size_t)row*DM;
  #pragma unroll
  for (int j=0;j<4;j++){
    int c = lane + j*64;
    float val = (j==0?d0:j==1?d1:j==2?d2:d3)*rstd*g[c] + b[c];
    ushort_t h = f2bf(val);
    xnh[ro+c] = h;
    xnl[ro+c] = f2bf(val - bf2f(h));
  }
}

// ---------------- split-bf16 MFMA GEMM: C[M,N] = A[M,K] @ B[N,K]^T ----------------
// EPI: 0 = fp32 C; 1 = fp32 C + bias; 2 = fp32 C AND bf16 planes;
//      4 = scatter x_dbl -> dtIn[row][16] + bc4[row][8 groups][B4|C4]
template<int BM, int EPI>
__global__ __launch_bounds__(256) void gemm_mfma(
    const ushort_t* __restrict__ Ahi, const ushort_t* __restrict__ Alo, long Az,
    const ushort_t* __restrict__ Bhi, const ushort_t* __restrict__ Blo,
    int K, int N,
    float* __restrict__ C, int ldc, int Czoff,
    ushort_t* __restrict__ Phi, ushort_t* __restrict__ Plo, int ldp,
    const float* __restrict__ bias, float* __restrict__ C2)
{
  constexpr int MT = (BM==128)?4:2;
  __shared__ ushort_t Al[BM][64];
  __shared__ ushort_t Bl[128][64];
  int tid = threadIdx.x;
  int z = blockIdx.z;
  const ushort_t* Ah = Ahi + (long)z*Az;
  const ushort_t* Alw = Alo + (long)z*Az;
  float* Cz = C + (long)z*Czoff;
  int bm0 = blockIdx.y*BM, bn0 = blockIdx.x*128;

  int w = tid>>6, l = tid&63;
  int wm = w>>1, wn = w&1;
  int lr = l&15, q = l>>4;

  f32x4 acc[MT][4];
  #pragma unroll
  for (int i=0;i<MT;i++)
    #pragma unroll
    for (int j=0;j<4;j++) acc[i][j] = (f32x4){0.f,0.f,0.f,0.f};

  for (int k0=0; k0<K; k0+=32){
    #pragma unroll
    for (int p=0; p<BM/32; ++p){
      int idx = p*256 + tid;
      int row = idx>>3, c8 = idx&7;
      int kq = c8>>1, pl = c8&1;
      const ushort_t* src = (pl? Alw : Ah) + (long)(bm0+row)*K + k0 + kq*8;
      uint4 v = *(const uint4*)src;
      *(uint4*)&Al[row][(c8 ^ (row&7))<<3] = v;
    }
    #pragma unroll
    for (int p=0; p<4; ++p){
      int idx = p*256 + tid;
      int row = idx>>3, c8 = idx&7;
      int kq = c8>>1, pl = c8&1;
      int rn = bn0+row; if (rn > N-1) rn = N-1;
      const ushort_t* src = (pl? Blo : Bhi) + (long)rn*K + k0 + kq*8;
      uint4 v = *(const uint4*)src;
      *(uint4*)&Bl[row][(c8 ^ (row&7))<<3] = v;
    }
    __syncthreads();
    bf16x8 bh[4], bl[4];
    #pragma unroll
    for (int nt=0; nt<4; ++nt){
      int r = wn*64 + nt*16 + lr;
      bh[nt] = *(const bf16x8*)&Bl[r][((2*q)   ^ (r&7))<<3];
      bl[nt] = *(const bf16x8*)&Bl[r][((2*q+1) ^ (r&7))<<3];
    }
    #pragma unroll
    for (int mt=0; mt<MT; ++mt){
      int r = wm*(BM/2) + mt*16 + lr;
      bf16x8 ah = *(const bf16x8*)&Al[r][((2*q)   ^ (r&7))<<3];
      bf16x8 al = *(const bf16x8*)&Al[r][((2*q+1) ^ (r&7))<<3];
      #pragma unroll
      for (int nt=0; nt<4; ++nt){
        acc[mt][nt] = __builtin_amdgcn_mfma_f32_16x16x32_bf16(al, bh[nt], acc[mt][nt], 0,0,0);
        acc[mt][nt] = __builtin_amdgcn_mfma_f32_16x16x32_bf16(ah, bl[nt], acc[mt][nt], 0,0,0);
        acc[mt][nt] = __builtin_amdgcn_mfma_f32_16x16x32_bf16(ah, bh[nt], acc[mt][nt], 0,0,0);
      }
    }
    __syncthreads();
  }
  // epilogue: C/D frag: col = lane&15, row = (lane>>4)*4 + reg
  #pragma unroll
  for (int mt=0; mt<MT; ++mt){
    #pragma unroll
    for (int nt=0; nt<4; ++nt){
      #pragma unroll
      for (int r=0; r<4; ++r){
        int row = bm0 + wm*(BM/2) + mt*16 + q*4 + r;
        int col = bn0 + wn*64 + nt*16 + lr;
        if (col < N){
          float v = acc[mt][nt][r];
          if (EPI==4){
            if (col < DTR)      C [(long)row*16 + col] = v;
            else if (col < 48){ int n = col-DTR;
                                C2[(long)row*64 + (n>>2)*8 + (n&3)] = v; }
            else              { int n = col-48;
                                C2[(long)row*64 + (n>>2)*8 + 4 + (n&3)] = v; }
          } else {
            if (EPI==1) v += bias[col];
            Cz[(long)row*ldc + col] = v;
            if (EPI==2){
              ushort_t h = f2bf(v);
              (Phi + (long)z*Czoff)[(long)row*ldp + col] = h;
              (Plo + (long)z*Czoff)[(long)row*ldp + col] = f2bf(v - bf2f(h));
            }
          }
        }
      }
    }
  }
}

// ---------------- depthwise conv (both dirs) + bias + SiLU -> bf16 hi/lo planes ----
template<int KC>
__global__ __launch_bounds__(256) void conv_kernel(
  const float* __restrict__ xz, const float* __restrict__ w, const float* __restrict__ cb,
  ushort_t* __restrict__ xih, ushort_t* __restrict__ xil)
{
  int idx = blockIdx.x*256 + threadIdx.x;   // R*DI/4 threads
  int c4 = (idx & 127) * 4;
  int t  = (idx >> 7) & (L_SEQ-1);
  int bb = idx >> 16;
  const float* base = xz + ((size_t)bb*L_SEQ)*1024 + c4;
  float4 wr[KC];
  #pragma unroll
  for (int j=0;j<KC;j++)
    wr[j] = make_float4(w[(c4+0)*KC+j], w[(c4+1)*KC+j],
                        w[(c4+2)*KC+j], w[(c4+3)*KC+j]);
  float4 bias = *(const float4*)&cb[c4];
  float4 aF = bias, aR = bias;
  #pragma unroll
  for (int j=0;j<KC;j++){
    int tf = t - (KC-1) + j;
    if (tf >= 0){
      float4 v = *(const float4*)&base[(size_t)tf*1024];
      aF.x = fmaf(wr[j].x, v.x, aF.x); aF.y = fmaf(wr[j].y, v.y, aF.y);
      aF.z = fmaf(wr[j].z, v.z, aF.z); aF.w = fmaf(wr[j].w, v.w, aF.w);
    }
    int tr = t + (KC-1) - j;
    if (tr < L_SEQ){
      float4 v = *(const float4*)&base[(size_t)tr*1024];
      aR.x = fmaf(wr[j].x, v.x, aR.x); aR.y = fmaf(wr[j].y, v.y, aR.y);
      aR.z = fmaf(wr[j].z, v.z, aR.z); aR.w = fmaf(wr[j].w, v.w, aR.w);
    }
  }
  float4 sF = make_float4(siluf(aF.x), siluf(aF.y), siluf(aF.z), siluf(aF.w));
  float4 sR = make_float4(siluf(aR.x), siluf(aR.y), siluf(aR.z), siluf(aR.w));
  const size_t RD = (size_t)R_ROWS*DI;
  size_t o = ((size_t)bb*L_SEQ + t)*DI + c4;
  ushort_t fh0=f2bf(sF.x), fh1=f2bf(sF.y), fh2=f2bf(sF.z), fh3=f2bf(sF.w);
  ushort_t rh0=f2bf(sR.x), rh1=f2bf(sR.y), rh2=f2bf(sR.z), rh3=f2bf(sR.w);
  uint2 pF = make_uint2((unsigned)fh0 | ((unsigned)fh1<<16), (unsigned)fh2 | ((unsigned)fh3<<16));
  uint2 pR = make_uint2((unsigned)rh0 | ((unsigned)rh1<<16), (unsigned)rh2 | ((unsigned)rh3<<16));
  *(uint2*)&xih[o]    = pF;
  *(uint2*)&xih[RD+o] = pR;
  uint2 lF = make_uint2((unsigned)f2bf(sF.x-bf2f(fh0)) | ((unsigned)f2bf(sF.y-bf2f(fh1))<<16),
                        (unsigned)f2bf(sF.z-bf2f(fh2)) | ((unsigned)f2bf(sF.w-bf2f(fh3))<<16));
  uint2 lR = make_uint2((unsigned)f2bf(sR.x-bf2f(rh0)) | ((unsigned)f2bf(sR.y-bf2f(rh1))<<16),
                        (unsigned)f2bf(sR.z-bf2f(rh2)) | ((unsigned)f2bf(sR.w-bf2f(rh3))<<16));
  *(uint2*)&xil[o]    = lF;
  *(uint2*)&xil[RD+o] = lR;
}

// ---------------- selective scan: 4 states/lane, 8 lanes/channel, 3-level DPP ----
// Grid 512 = dgrp(16 of 32ch) x slice(32 = m,dir,b). bi = dgrp*32 + slice so the
// 16 blocks sharing one bcI slice land on one XCD (bi%8 = b). Block = 256 thr =
// 4 waves x (8 ch x 8 ngrp). Lane owns h[4]; B/C via two float4 global loads.
__global__ __launch_bounds__(256) void scan_kernel(
  const float* __restrict__ dtIn,  // [2][2R][16]
  const float* __restrict__ bc4,   // [2][2R][64]: per row 8x{B4,C4}
  const ushort_t* __restrict__ xih,// [2][2R][512]
  const ushort_t* __restrict__ xil,
  const float* __restrict__ xz,    // [2][R][1024] (z = cols 512..1023)
  const float* __restrict__ Wdt0, const float* __restrict__ Wdt1,   // [512,16]
  const float* __restrict__ dtb0, const float* __restrict__ dtb1,
  const float* __restrict__ Alog0,const float* __restrict__ Alog1,  // [512,32]
  const float* __restrict__ Dp0,  const float* __restrict__ Dp1,
  ushort_t* __restrict__ yh, ushort_t* __restrict__ yl)  // [2(dir)][R][1024], col m*512
{
  int bi = blockIdx.x;
  int dgrp = bi >> 5, slice = bi & 31;
  int m = slice >> 4, dir = (slice >> 3) & 1, b = slice & 7;
  int d0 = dgrp * 32;
  const float* WdtW = m ? Wdt1 : Wdt0;
  const float* dtbp = m ? dtb1 : dtb0;
  const float* Alog = m ? Alog1 : Alog0;
  const float* Dp   = m ? Dp1   : Dp0;
  size_t md = (size_t)m*2 + dir;
  const float*    dtp = dtIn + md*R_ROWS*16;
  const float*    bcp = bc4  + md*R_ROWS*64;
  const ushort_t* xhp = xih  + md*R_ROWS*DI;
  const ushort_t* xlp = xil  + md*R_ROWS*DI;
  const float*    zp  = xz   + (size_t)m*R_ROWS*1024;
  ushort_t* yoh = yh + (size_t)dir*R_ROWS*1024 + m*512;
  ushort_t* yol = yl + (size_t)dir*R_ROWS*1024 + m*512;
  size_t bL = (size_t)b*L_SEQ;

  __shared__ float2 DTDX[32][33];   // [ch][t] (dt, dt*xi)
  __shared__ float2 XZt[32][33];    // [ch][t] (xi, z)
  __shared__ float  YOT[32][33];    // [ch][t] y out

  int tid = threadIdx.x;
  int wv = tid>>6, l64 = tid&63;
  int chw = l64>>3;                 // channel within wave 0..7
  int chl = wv*8 + chw;             // channel within block 0..31
  int ngrp = l64 & 7;               // state group: n = ngrp*4..+3
  int d = d0 + chl;

  // per-lane state-group constants
  f32x4 Alv;
  {
    const float4 a = *(const float4*)&Alog[d*NSTATE + ngrp*4];
    Alv[0] = -__expf(a.x) * 1.44269504089f;
    Alv[1] = -__expf(a.y) * 1.44269504089f;
    Alv[2] = -__expf(a.z) * 1.44269504089f;
    Alv[3] = -__expf(a.w) * 1.44269504089f;
  }
  float Dpv = Dp[d];
  // staging constants: thread handles channel cs = d0 + (tid&31)
  int cs = tid & 31;
  const float4* wp = (const float4*)&WdtW[(d0+cs)*DTR];
  float4 w0 = wp[0], w1 = wp[1], w2 = wp[2], w3 = wp[3];
  float dtbv = dtbp[d0+cs];
  bool writer = (ngrp == 0);
  float h0=0.f, h1=0.f, h2=0.f, h3=0.f;

  for (int chunk=0; chunk<16; ++chunk){
    int s0 = chunk*32;
    // E: write previous chunk's y (coalesced over 32 ch per t)
    if (chunk){
      #pragma unroll
      for (int k=0;k<4;k++){
        int e = tid + k*256;
        int tl = e>>5, cc = e&31;
        int st = s0 - 32 + tl;
        int t = dir ? (L_SEQ-1-st) : st;
        float v = YOT[cc][tl];
        ushort_t hh = f2bf(v);
        yoh[(bL + t)*1024 + d0 + cc] = hh;
        yol[(bL + t)*1024 + d0 + cc] = f2bf(v - bf2f(hh));
      }
    }
    // B: stage dt (softplus of 16-dot), dt*xi, (xi,z); thread = (cs, 4 t's)
    #pragma unroll
    for (int k=0;k<4;k++){
      int tl = (tid>>5) + k*8;
      int st = s0 + tl;
      int t = dir ? (L_SEQ-1-st) : st;
      size_t row = bL + t;
      const float4* dp = (const float4*)&dtp[row*16];
      float4 a0 = dp[0], a1 = dp[1], a2 = dp[2], a3 = dp[3];
      float s = dtbv;
      s = fmaf(a0.x,w0.x, fmaf(a0.y,w0.y, fmaf(a0.z,w0.z, fmaf(a0.w,w0.w, s))));
      s = fmaf(a1.x,w1.x, fmaf(a1.y,w1.y, fmaf(a1.z,w1.z, fmaf(a1.w,w1.w, s))));
      s = fmaf(a2.x,w2.x, fmaf(a2.y,w2.y, fmaf(a2.z,w2.z, fmaf(a2.w,w2.w, s))));
      s = fmaf(a3.x,w3.x, fmaf(a3.y,w3.y, fmaf(a3.z,w3.z, fmaf(a3.w,w3.w, s))));
      float dtv = fmaxf(s,0.f) + log1pf(__expf(-fabsf(s)));
      float xiv = bf2f(xhp[row*DI + d0 + cs]) + bf2f(xlp[row*DI + d0 + cs]);
      float zv  = zp[row*1024 + DI + d0 + cs];
      DTDX[cs][tl] = make_float2(dtv, dtv * xiv);
      XZt[cs][tl]  = make_float2(xiv, zv);
    }
    __syncthreads();
    // steps: 32 per chunk
    #pragma unroll 4
    for (int tl=0; tl<32; ++tl){
      int st = s0 + tl;
      int t = dir ? (L_SEQ-1-st) : st;
      const float* bp = &bcp[(bL + t)*64 + ngrp*8];
      float4 B4 = *(const float4*)bp;
      float4 C4 = *(const float4*)(bp+4);
      float2 dd = DTDX[chl][tl];
      h0 = fmaf(__builtin_amdgcn_exp2f(dd.x*Alv[0]), h0, dd.y*B4.x);
      h1 = fmaf(__builtin_amdgcn_exp2f(dd.x*Alv[1]), h1, dd.y*B4.y);
      h2 = fmaf(__builtin_amdgcn_exp2f(dd.x*Alv[2]), h2, dd.y*B4.z);
      h3 = fmaf(__builtin_amdgcn_exp2f(dd.x*Alv[3]), h3, dd.y*B4.w);
      float yp = fmaf(h3, C4.w, fmaf(h2, C4.z, fmaf(h1, C4.y, h0*C4.x)));
      yp = dpp_add<0xB1>(yp);    // xor1
      yp = dpp_add<0x4E>(yp);    // xor2
      yp = dpp_add<0x141>(yp);   // half-mirror == xor4 after levels 1,2
      if (writer){
        float2 xzv = XZt[chl][tl];
        YOT[chl][tl] = (yp + xzv.x*Dpv) * siluf(xzv.y);
      }
    }
    __syncthreads();
  }
  // final E (chunk 15)
  #pragma unroll
  for (int k=0;k<4;k++){
    int e = tid + k*256;
    int tl = e>>5, cc = e&31;
    int st = 480 + tl;
    int t = dir ? (L_SEQ-1-st) : st;
    float v = YOT[cc][tl];
    ushort_t hh = f2bf(v);
    yoh[(bL + t)*1024 + d0 + cc] = hh;
    yol[(bL + t)*1024 + d0 + cc] = f2bf(v - bf2f(hh));
  }
}

// ---------------- gate + fuse -> bf16 planes of fused ----------------
__global__ __launch_bounds__(256) void fuse_kernel(const float* __restrict__ gpre,
   const float* __restrict__ gb, const float* __restrict__ ffr,
   ushort_t* __restrict__ fush, ushort_t* __restrict__ fusl)
{
  int idx = blockIdx.x*256 + threadIdx.x;
  int r = idx >> 8, c = idx & (DM-1);
  size_t ro = (size_t)r*2*DM;
  float ffv = ffr[ro + c];
  float frv = ffr[ro + DM + c];
  float g = 1.f/(1.f+__expf(-(gpre[idx] + gb[c])));
  float v = g*ffv + (1.f-g)*frv;
  ushort_t h = f2bf(v);
  fush[idx] = h;
  fusl[idx] = f2bf(v - bf2f(h));
}

extern "C" void kernel_launch(void* const* d_in, const int* in_sizes, int n_in,
                              void* d_out, int out_size, void* d_ws, size_t ws_size,
                              hipStream_t stream)
{
  (void)in_sizes; (void)n_in; (void)out_size; (void)ws_size;
  const float* x    = (const float*)d_in[0];
  const float* ln_g = (const float*)d_in[1];
  const float* ln_b = (const float*)d_in[2];
  const float* Win[2]  = {(const float*)d_in[3],  (const float*)d_in[12]};
  const float* convw[2]= {(const float*)d_in[4],  (const float*)d_in[13]};
  const float* convb[2]= {(const float*)d_in[5],  (const float*)d_in[14]};
  const float* Wx[2]   = {(const float*)d_in[6],  (const float*)d_in[15]};
  const float* Wdt[2]  = {(const float*)d_in[7],  (const float*)d_in[16]};
  const float* dtb[2]  = {(const float*)d_in[8],  (const float*)d_in[17]};
  const float* Alog[2] = {(const float*)d_in[9],  (const float*)d_in[18]};
  const float* Dpp[2]  = {(const float*)d_in[10], (const float*)d_in[19]};
  const float* Wout[2] = {(const float*)d_in[11], (const float*)d_in[20]};
  const float* gate_W = (const float*)d_in[21];
  const float* gate_b = (const float*)d_in[22];
  const float* op_W   = (const float*)d_in[23];
  const float* op_b   = (const float*)d_in[24];
  float* out = (float*)d_out;

  char* wsb = (char*)d_ws;
  size_t off = 0;
  auto allocB = [&](size_t bytes)->char*{
    char* p = wsb + off; off += (bytes + 255) & ~size_t(255); return p; };
  const size_t R = R_ROWS;

  // persistent region
  float* xzb  = (float*)allocB(2*R*1024*4);        // [m][R][1024]
  float* dtIn = (float*)allocB(2*2*R*16*4);        // [m][dir R][16]
  float* bc4  = (float*)allocB(2*2*R*64*4);        // [m][dir R][64]
  ushort_t* xnh = (ushort_t*)allocB(R*DM*2);
  ushort_t* xnl = (ushort_t*)allocB(R*DM*2);
  ushort_t* yhp = (ushort_t*)allocB(2*R*1024*2);   // [dir][R][1024], col m*512
  ushort_t* ylp = (ushort_t*)allocB(2*R*1024*2);
  // weight planes
  ushort_t* WiH[2] = {(ushort_t*)allocB(262144*2), (ushort_t*)allocB(262144*2)};
  ushort_t* WiL[2] = {(ushort_t*)allocB(262144*2), (ushort_t*)allocB(262144*2)};
  ushort_t* WxH[2] = {(ushort_t*)allocB(40960*2),  (ushort_t*)allocB(40960*2)};
  ushort_t* WxL[2] = {(ushort_t*)allocB(40960*2),  (ushort_t*)allocB(40960*2)};
  ushort_t* WoH = (ushort_t*)allocB(262144*2);
  ushort_t* WoL = (ushort_t*)allocB(262144*2);
  ushort_t* gH  = (ushort_t*)allocB(131072*2);
  ushort_t* gL  = (ushort_t*)allocB(131072*2);
  ushort_t* oH  = (ushort_t*)allocB(65536*2);
  ushort_t* oL  = (ushort_t*)allocB(65536*2);

  // union region: phase1 = xih/xil (live through scan); phase2 = post-scan buffers
  size_t uo = off;
  ushort_t* xih = (ushort_t*)allocB(2*2*R*DI*2);   // [m][dir R][512]
  ushort_t* xil = (ushort_t*)allocB(2*2*R*DI*2);
  // phase2 overlays (written only after scan completes)
  char* p2 = wsb + uo;
  float* ffr  = (float*)p2;              p2 += (size_t)R*2*DM*4;
  float* gpre = (float*)p2;              p2 += (size_t)R*DM*4;
  ushort_t* ffh = (ushort_t*)p2;         p2 += (size_t)R*2*DM*2;
  ushort_t* ffl = (ushort_t*)p2;         p2 += (size_t)R*2*DM*2;
  ushort_t* fsh = (ushort_t*)p2;         p2 += (size_t)R*DM*2;
  ushort_t* fsl = (ushort_t*)p2;         p2 += (size_t)R*DM*2;

  prep_weights<<<4160, 256, 0, stream>>>(Win[0], Win[1], Wx[0], Wx[1],
      Wout[0], Wout[1], gate_W, op_W,
      WiH[0], WiL[0], WiH[1], WiL[1], WxH[0], WxL[0], WxH[1], WxL[1],
      WoH, WoL, gH, gL, oH, oL);

  ln_kernel<<<R/4, 256, 0, stream>>>(x, ln_g, ln_b, xnh, xnl);

  for (int m=0; m<2; ++m){
    float* xzm = xzb + (size_t)m*R*1024;
    ushort_t* xihm = xih + (size_t)m*2*R*DI;
    ushort_t* xilm = xil + (size_t)m*2*R*DI;
    // xz = xn @ Win^T   [4096,256] x [1024,256]^T
    gemm_mfma<128,0><<<dim3(8, 32, 1), 256, 0, stream>>>(
        xnh, xnl, 0, WiH[m], WiL[m], DM, 1024, xzm, 1024, 0,
        nullptr, nullptr, 0, nullptr, nullptr);
    if (m==0) conv_kernel<4><<<2048,256,0,stream>>>(xzm, convw[m], convb[m], xihm, xilm);
    else      conv_kernel<8><<<2048,256,0,stream>>>(xzm, convw[m], convb[m], xihm, xilm);
    // x_dbl = xi @ Wx^T -> dtIn + bc4   [8192,512] x [80,512]^T
    gemm_mfma<64,4><<<dim3(1, 128, 1), 256, 0, stream>>>(
        xihm, xilm, 0, WxH[m], WxL[m], DI, 80, dtIn + (size_t)m*2*R*16, 16, 0,
        nullptr, nullptr, 0, nullptr, bc4 + (size_t)m*2*R*64);
  }
  // ONE merged scan: 512 blocks (XCD-local slices)
  scan_kernel<<<512, 256, 0, stream>>>(dtIn, bc4, xih, xil, xzb,
      Wdt[0], Wdt[1], dtb[0], dtb[1], Alog[0], Alog[1], Dpp[0], Dpp[1],
      yhp, ylp);
  // f_dir = y[dir] @ [Wout0;Wout1]^T  (K=1024), z=dir -> ffr cols dir*256..
  gemm_mfma<128,2><<<dim3(2, 32, 2), 256, 0, stream>>>(
      yhp, ylp, (long)R*1024, WoH, WoL, 1024, 256, ffr, 2*DM, DM,
      ffh, ffl, 2*DM, nullptr, nullptr);
  // gate pre-activation: ffr @ gate_W^T  [4096,512] x [256,512]^T
  gemm_mfma<64,0><<<dim3(2, 64, 1), 256, 0, stream>>>(
      ffh, ffl, 0, gH, gL, 2*DM, DM, gpre, DM, 0,
      nullptr, nullptr, 0, nullptr, nullptr);
  fuse_kernel<<<R*DM/256, 256, 0, stream>>>(gpre, gate_b, ffr, fsh, fsl);
  // out = fused @ op_W^T + op_b
  gemm_mfma<64,1><<<dim3(2, 64, 1), 256, 0, stream>>>(
      fsh, fsl, 0, oH, oL, DM, DM, out, DM, 0,
      nullptr, nullptr, 0, op_b, nullptr);
}

// Round 10
// 415.203 us; speedup vs baseline: 1.4936x; 1.2980x over previous
//
#include <hip/hip_runtime.h>
#include <math.h>

#define L_SEQ 512
#define NB 8
#define DM 256
#define DI 512
#define NSTATE 32
#define DTR 16
#define R_ROWS 4096   // NB*L_SEQ

typedef unsigned short ushort_t;
typedef __bf16 bf16t;
typedef bf16t bf16x8 __attribute__((ext_vector_type(8)));
typedef float f32x4 __attribute__((ext_vector_type(4)));

static __device__ __forceinline__ float siluf(float x){
  return x / (1.f + __expf(-x));
}
static __device__ __forceinline__ ushort_t f2bf(float f){
  unsigned u = __float_as_uint(f);
  u += 0x7fff + ((u>>16)&1);
  return (ushort_t)(u>>16);
}
static __device__ __forceinline__ float bf2f(ushort_t h){
  return __uint_as_float(((unsigned)h)<<16);
}
// VALU cross-lane add via DPP (no DS pipe)
template<int CTRL>
static __device__ __forceinline__ float dpp_add(float v){
  int t = __builtin_amdgcn_update_dpp(0, __float_as_int(v), CTRL, 0xF, 0xF, true);
  return v + __int_as_float(t);
}

// ---------------- weight prep: fp32 -> bf16 hi/lo planes ----------------
__global__ __launch_bounds__(256) void prep_weights(
  const float* __restrict__ Wi0, const float* __restrict__ Wi1,
  const float* __restrict__ Wx0, const float* __restrict__ Wx1,
  const float* __restrict__ Wo0, const float* __restrict__ Wo1,
  const float* __restrict__ gW,  const float* __restrict__ oW,
  ushort_t* WiH0, ushort_t* WiL0, ushort_t* WiH1, ushort_t* WiL1,
  ushort_t* WxH0, ushort_t* WxL0, ushort_t* WxH1, ushort_t* WxL1,
  ushort_t* WoH,  ushort_t* WoL,  ushort_t* gH, ushort_t* gL,
  ushort_t* oH, ushort_t* oL)
{
  int i = blockIdx.x*256 + threadIdx.x;
  float v; ushort_t *ph, *pl; int oi;
  if (i < 262144){ v = Wi0[i]; ph=WiH0; pl=WiL0; oi=i; }
  else if (i < 524288){ oi=i-262144; v = Wi1[oi]; ph=WiH1; pl=WiL1; }
  else if (i < 565248){ oi=i-524288; v = Wx0[oi]; ph=WxH0; pl=WxL0; }
  else if (i < 606208){ oi=i-565248; v = Wx1[oi]; ph=WxH1; pl=WxL1; }
  else if (i < 868352){ oi=i-606208; int n=oi>>10, k=oi&1023;
                        v = (k<512)? Wo0[n*512+k] : Wo1[n*512+k-512];
                        ph=WoH; pl=WoL; }
  else if (i < 999424){ oi=i-868352; v = gW[oi]; ph=gH; pl=gL; }
  else { oi=i-999424; v = oW[oi]; ph=oH; pl=oL; }
  ushort_t h = f2bf(v);
  ph[oi] = h;
  pl[oi] = f2bf(v - bf2f(h));
}

// ---------------- LayerNorm -> bf16 hi/lo planes ----------------
__global__ __launch_bounds__(256) void ln_kernel(const float* __restrict__ x,
    const float* __restrict__ g, const float* __restrict__ b,
    ushort_t* __restrict__ xnh, ushort_t* __restrict__ xnl)
{
  int row = blockIdx.x*4 + (threadIdx.x>>6);
  int lane = threadIdx.x & 63;
  const float* xr = x + (size_t)row*DM;
  float v0 = xr[lane], v1 = xr[lane+64], v2 = xr[lane+128], v3 = xr[lane+192];
  float s = v0+v1+v2+v3;
  #pragma unroll
  for (int m=1;m<64;m<<=1) s += __shfl_xor(s, m);
  float mu = s*(1.f/DM);
  float d0=v0-mu,d1=v1-mu,d2=v2-mu,d3=v3-mu;
  float vs = d0*d0+d1*d1+d2*d2+d3*d3;
  #pragma unroll
  for (int m=1;m<64;m<<=1) vs += __shfl_xor(vs, m);
  float rstd = rsqrtf(vs*(1.f/DM)+1e-5f);
  size_t ro = (size_t)row*DM;
  #pragma unroll
  for (int j=0;j<4;j++){
    int c = lane + j*64;
    float val = (j==0?d0:j==1?d1:j==2?d2:d3)*rstd*g[c] + b[c];
    ushort_t h = f2bf(val);
    xnh[ro+c] = h;
    xnl[ro+c] = f2bf(val - bf2f(h));
  }
}

// ---------------- split-bf16 MFMA GEMM: C[M,N] = A[M,K] @ B[N,K]^T ----------------
// EPI: 0 = fp32 C; 1 = fp32 C + bias; 2 = fp32 C AND bf16 planes;
//      4 = scatter x_dbl -> dtIn[row][16] + bc4[row][8 groups][B4|C4]
template<int BM, int EPI>
__global__ __launch_bounds__(256) void gemm_mfma(
    const ushort_t* __restrict__ Ahi, const ushort_t* __restrict__ Alo, long Az,
    const ushort_t* __restrict__ Bhi, const ushort_t* __restrict__ Blo,
    int K, int N,
    float* __restrict__ C, int ldc, int Czoff,
    ushort_t* __restrict__ Phi, ushort_t* __restrict__ Plo, int ldp,
    const float* __restrict__ bias, float* __restrict__ C2)
{
  constexpr int MT = (BM==128)?4:2;
  __shared__ ushort_t Al[BM][64];
  __shared__ ushort_t Bl[128][64];
  int tid = threadIdx.x;
  int z = blockIdx.z;
  const ushort_t* Ah = Ahi + (long)z*Az;
  const ushort_t* Alw = Alo + (long)z*Az;
  float* Cz = C + (long)z*Czoff;
  int bm0 = blockIdx.y*BM, bn0 = blockIdx.x*128;

  int w = tid>>6, l = tid&63;
  int wm = w>>1, wn = w&1;
  int lr = l&15, q = l>>4;

  f32x4 acc[MT][4];
  #pragma unroll
  for (int i=0;i<MT;i++)
    #pragma unroll
    for (int j=0;j<4;j++) acc[i][j] = (f32x4){0.f,0.f,0.f,0.f};

  for (int k0=0; k0<K; k0+=32){
    #pragma unroll
    for (int p=0; p<BM/32; ++p){
      int idx = p*256 + tid;
      int row = idx>>3, c8 = idx&7;
      int kq = c8>>1, pl = c8&1;
      const ushort_t* src = (pl? Alw : Ah) + (long)(bm0+row)*K + k0 + kq*8;
      uint4 v = *(const uint4*)src;
      *(uint4*)&Al[row][(c8 ^ (row&7))<<3] = v;
    }
    #pragma unroll
    for (int p=0; p<4; ++p){
      int idx = p*256 + tid;
      int row = idx>>3, c8 = idx&7;
      int kq = c8>>1, pl = c8&1;
      int rn = bn0+row; if (rn > N-1) rn = N-1;
      const ushort_t* src = (pl? Blo : Bhi) + (long)rn*K + k0 + kq*8;
      uint4 v = *(const uint4*)src;
      *(uint4*)&Bl[row][(c8 ^ (row&7))<<3] = v;
    }
    __syncthreads();
    bf16x8 bh[4], bl[4];
    #pragma unroll
    for (int nt=0; nt<4; ++nt){
      int r = wn*64 + nt*16 + lr;
      bh[nt] = *(const bf16x8*)&Bl[r][((2*q)   ^ (r&7))<<3];
      bl[nt] = *(const bf16x8*)&Bl[r][((2*q+1) ^ (r&7))<<3];
    }
    #pragma unroll
    for (int mt=0; mt<MT; ++mt){
      int r = wm*(BM/2) + mt*16 + lr;
      bf16x8 ah = *(const bf16x8*)&Al[r][((2*q)   ^ (r&7))<<3];
      bf16x8 al = *(const bf16x8*)&Al[r][((2*q+1) ^ (r&7))<<3];
      #pragma unroll
      for (int nt=0; nt<4; ++nt){
        acc[mt][nt] = __builtin_amdgcn_mfma_f32_16x16x32_bf16(al, bh[nt], acc[mt][nt], 0,0,0);
        acc[mt][nt] = __builtin_amdgcn_mfma_f32_16x16x32_bf16(ah, bl[nt], acc[mt][nt], 0,0,0);
        acc[mt][nt] = __builtin_amdgcn_mfma_f32_16x16x32_bf16(ah, bh[nt], acc[mt][nt], 0,0,0);
      }
    }
    __syncthreads();
  }
  // epilogue: C/D frag: col = lane&15, row = (lane>>4)*4 + reg
  #pragma unroll
  for (int mt=0; mt<MT; ++mt){
    #pragma unroll
    for (int nt=0; nt<4; ++nt){
      #pragma unroll
      for (int r=0; r<4; ++r){
        int row = bm0 + wm*(BM/2) + mt*16 + q*4 + r;
        int col = bn0 + wn*64 + nt*16 + lr;
        if (col < N){
          float v = acc[mt][nt][r];
          if (EPI==4){
            if (col < DTR)      C [(long)row*16 + col] = v;
            else if (col < 48){ int n = col-DTR;
                                C2[(long)row*64 + (n>>2)*8 + (n&3)] = v; }
            else              { int n = col-48;
                                C2[(long)row*64 + (n>>2)*8 + 4 + (n&3)] = v; }
          } else {
            if (EPI==1) v += bias[col];
            Cz[(long)row*ldc + col] = v;
            if (EPI==2){
              ushort_t h = f2bf(v);
              (Phi + (long)z*Czoff)[(long)row*ldp + col] = h;
              (Plo + (long)z*Czoff)[(long)row*ldp + col] = f2bf(v - bf2f(h));
            }
          }
        }
      }
    }
  }
}

// ---------------- depthwise conv (both dirs) + bias + SiLU -> bf16 hi/lo planes ----
template<int KC>
__global__ __launch_bounds__(256) void conv_kernel(
  const float* __restrict__ xz, const float* __restrict__ w, const float* __restrict__ cb,
  ushort_t* __restrict__ xih, ushort_t* __restrict__ xil)
{
  int idx = blockIdx.x*256 + threadIdx.x;   // R*DI/4 threads
  int c4 = (idx & 127) * 4;
  int t  = (idx >> 7) & (L_SEQ-1);
  int bb = idx >> 16;
  const float* base = xz + ((size_t)bb*L_SEQ)*1024 + c4;
  float4 wr[KC];
  #pragma unroll
  for (int j=0;j<KC;j++)
    wr[j] = make_float4(w[(c4+0)*KC+j], w[(c4+1)*KC+j],
                        w[(c4+2)*KC+j], w[(c4+3)*KC+j]);
  float4 bias = *(const float4*)&cb[c4];
  float4 aF = bias, aR = bias;
  #pragma unroll
  for (int j=0;j<KC;j++){
    int tf = t - (KC-1) + j;
    if (tf >= 0){
      float4 v = *(const float4*)&base[(size_t)tf*1024];
      aF.x = fmaf(wr[j].x, v.x, aF.x); aF.y = fmaf(wr[j].y, v.y, aF.y);
      aF.z = fmaf(wr[j].z, v.z, aF.z); aF.w = fmaf(wr[j].w, v.w, aF.w);
    }
    int tr = t + (KC-1) - j;
    if (tr < L_SEQ){
      float4 v = *(const float4*)&base[(size_t)tr*1024];
      aR.x = fmaf(wr[j].x, v.x, aR.x); aR.y = fmaf(wr[j].y, v.y, aR.y);
      aR.z = fmaf(wr[j].z, v.z, aR.z); aR.w = fmaf(wr[j].w, v.w, aR.w);
    }
  }
  float4 sF = make_float4(siluf(aF.x), siluf(aF.y), siluf(aF.z), siluf(aF.w));
  float4 sR = make_float4(siluf(aR.x), siluf(aR.y), siluf(aR.z), siluf(aR.w));
  const size_t RD = (size_t)R_ROWS*DI;
  size_t o = ((size_t)bb*L_SEQ + t)*DI + c4;
  ushort_t fh0=f2bf(sF.x), fh1=f2bf(sF.y), fh2=f2bf(sF.z), fh3=f2bf(sF.w);
  ushort_t rh0=f2bf(sR.x), rh1=f2bf(sR.y), rh2=f2bf(sR.z), rh3=f2bf(sR.w);
  uint2 pF = make_uint2((unsigned)fh0 | ((unsigned)fh1<<16), (unsigned)fh2 | ((unsigned)fh3<<16));
  uint2 pR = make_uint2((unsigned)rh0 | ((unsigned)rh1<<16), (unsigned)rh2 | ((unsigned)rh3<<16));
  *(uint2*)&xih[o]    = pF;
  *(uint2*)&xih[RD+o] = pR;
  uint2 lF = make_uint2((unsigned)f2bf(sF.x-bf2f(fh0)) | ((unsigned)f2bf(sF.y-bf2f(fh1))<<16),
                        (unsigned)f2bf(sF.z-bf2f(fh2)) | ((unsigned)f2bf(sF.w-bf2f(fh3))<<16));
  uint2 lR = make_uint2((unsigned)f2bf(sR.x-bf2f(rh0)) | ((unsigned)f2bf(sR.y-bf2f(rh1))<<16),
                        (unsigned)f2bf(sR.z-bf2f(rh2)) | ((unsigned)f2bf(sR.w-bf2f(rh3))<<16));
  *(uint2*)&xil[o]    = lF;
  *(uint2*)&xil[RD+o] = lR;
}

// ---------------- selective scan: LDS-staged B/C + 2-deep register pipeline ----
// Grid 512 = dgrp(16) x slice(32 = m,dir,b); 256 thr = 4 waves x (8 ch x 8 ngrp).
// Lane owns h[4]. bc4 staged per-chunk in LDS; inner loop double-buffers groups
// of 4 steps in named registers (no runtime-indexed arrays -> no scratch).
__global__ __launch_bounds__(256) void scan_kernel(
  const float* __restrict__ dtIn,  // [2][2R][16]
  const float* __restrict__ bc4,   // [2][2R][64]: per row 8x{B4,C4}
  const ushort_t* __restrict__ xih,// [2][2R][512]
  const ushort_t* __restrict__ xil,
  const float* __restrict__ xz,    // [2][R][1024] (z = cols 512..1023)
  const float* __restrict__ Wdt0, const float* __restrict__ Wdt1,   // [512,16]
  const float* __restrict__ dtb0, const float* __restrict__ dtb1,
  const float* __restrict__ Alog0,const float* __restrict__ Alog1,  // [512,32]
  const float* __restrict__ Dp0,  const float* __restrict__ Dp1,
  ushort_t* __restrict__ yh, ushort_t* __restrict__ yl)  // [2(dir)][R][1024], col m*512
{
  int bi = blockIdx.x;
  int dgrp = bi >> 5, slice = bi & 31;
  int m = slice >> 4, dir = (slice >> 3) & 1, b = slice & 7;
  int d0 = dgrp * 32;
  const float* WdtW = m ? Wdt1 : Wdt0;
  const float* dtbp = m ? dtb1 : dtb0;
  const float* Alog = m ? Alog1 : Alog0;
  const float* Dp   = m ? Dp1   : Dp0;
  size_t md = (size_t)m*2 + dir;
  const float*    dtp = dtIn + md*R_ROWS*16;
  const float*    bcp = bc4  + md*R_ROWS*64;
  const ushort_t* xhp = xih  + md*R_ROWS*DI;
  const ushort_t* xlp = xil  + md*R_ROWS*DI;
  const float*    zp  = xz   + (size_t)m*R_ROWS*1024;
  ushort_t* yoh = yh + (size_t)dir*R_ROWS*1024 + m*512;
  ushort_t* yol = yl + (size_t)dir*R_ROWS*1024 + m*512;
  size_t bL = (size_t)b*L_SEQ;

  __shared__ float2 DTDX[32][33];   // [ch][t] (dt, dt*xi)
  __shared__ float2 XZt[32][33];    // [ch][t] (xi, z)
  __shared__ float  YOT[32][33];    // [ch][t] y out
  __shared__ float  BCS[32][64];    // [t][8 ngrp][B4|C4] staged per chunk

  int tid = threadIdx.x;
  int wv = tid>>6, l64 = tid&63;
  int chw = l64>>3;                 // channel within wave 0..7
  int chl = wv*8 + chw;             // channel within block 0..31
  int ngrp = l64 & 7;               // state group: n = ngrp*4..+3
  int ng8 = ngrp*8;
  int d = d0 + chl;

  f32x4 Alv;
  {
    const float4 a = *(const float4*)&Alog[d*NSTATE + ngrp*4];
    Alv[0] = -__expf(a.x) * 1.44269504089f;
    Alv[1] = -__expf(a.y) * 1.44269504089f;
    Alv[2] = -__expf(a.z) * 1.44269504089f;
    Alv[3] = -__expf(a.w) * 1.44269504089f;
  }
  float Dpv = Dp[d];
  int cs = tid & 31;
  const float4* wp = (const float4*)&WdtW[(d0+cs)*DTR];
  float4 w0 = wp[0], w1 = wp[1], w2 = wp[2], w3 = wp[3];
  float dtbv = dtbp[d0+cs];
  bool writer = (ngrp == 0);
  float h0=0.f, h1=0.f, h2=0.f, h3=0.f;

#define LDGRP(P, T4) { \
    const float* _b; \
    _b=&BCS[(T4)  ][ng8]; P##B0=*(const float4*)_b; P##C0=*(const float4*)(_b+4); \
    _b=&BCS[(T4)+1][ng8]; P##B1=*(const float4*)_b; P##C1=*(const float4*)(_b+4); \
    _b=&BCS[(T4)+2][ng8]; P##B2=*(const float4*)_b; P##C2=*(const float4*)(_b+4); \
    _b=&BCS[(T4)+3][ng8]; P##B3=*(const float4*)_b; P##C3=*(const float4*)(_b+4); \
    P##d0=DTDX[chl][(T4)]; P##d1=DTDX[chl][(T4)+1]; \
    P##d2=DTDX[chl][(T4)+2]; P##d3=DTDX[chl][(T4)+3]; \
    P##x0=XZt[chl][(T4)]; P##x1=XZt[chl][(T4)+1]; \
    P##x2=XZt[chl][(T4)+2]; P##x3=XZt[chl][(T4)+3]; }

#define STEP(Bv,Cv,dv,xv,TL) { \
    float _e0=__builtin_amdgcn_exp2f(dv.x*Alv[0]); \
    float _e1=__builtin_amdgcn_exp2f(dv.x*Alv[1]); \
    float _e2=__builtin_amdgcn_exp2f(dv.x*Alv[2]); \
    float _e3=__builtin_amdgcn_exp2f(dv.x*Alv[3]); \
    h0=fmaf(_e0,h0,dv.y*Bv.x); h1=fmaf(_e1,h1,dv.y*Bv.y); \
    h2=fmaf(_e2,h2,dv.y*Bv.z); h3=fmaf(_e3,h3,dv.y*Bv.w); \
    float _yp=fmaf(h3,Cv.w,fmaf(h2,Cv.z,fmaf(h1,Cv.y,h0*Cv.x))); \
    _yp=dpp_add<0xB1>(_yp); _yp=dpp_add<0x4E>(_yp); _yp=dpp_add<0x141>(_yp); \
    if (writer) YOT[chl][TL] = (_yp + xv.x*Dpv) * siluf(xv.y); }

#define CMPGRP(P, T4) \
    STEP(P##B0,P##C0,P##d0,P##x0,(T4))   STEP(P##B1,P##C1,P##d1,P##x1,(T4)+1) \
    STEP(P##B2,P##C2,P##d2,P##x2,(T4)+2) STEP(P##B3,P##C3,P##d3,P##x3,(T4)+3)

  float4 pB0,pB1,pB2,pB3, pC0,pC1,pC2,pC3;
  float2 pd0,pd1,pd2,pd3, px0,px1,px2,px3;
  float4 qB0,qB1,qB2,qB3, qC0,qC1,qC2,qC3;
  float2 qd0,qd1,qd2,qd3, qx0,qx1,qx2,qx3;

  for (int chunk=0; chunk<16; ++chunk){
    int s0 = chunk*32;
    // E: write previous chunk's y (coalesced over 32 ch per t)
    if (chunk){
      #pragma unroll
      for (int k=0;k<4;k++){
        int e = tid + k*256;
        int tl = e>>5, cc = e&31;
        int st = s0 - 32 + tl;
        int t = dir ? (L_SEQ-1-st) : st;
        float v = YOT[cc][tl];
        ushort_t hh = f2bf(v);
        yoh[(bL + t)*1024 + d0 + cc] = hh;
        yol[(bL + t)*1024 + d0 + cc] = f2bf(v - bf2f(hh));
      }
    }
    // B1: stage bc chunk (32 t x 64 floats) into LDS
    {
      int tl = tid>>3, seg = tid&7;
      int st = s0 + tl;
      int t = dir ? (L_SEQ-1-st) : st;
      const float* src = &bcp[(bL + t)*64 + seg*8];
      *(float4*)&BCS[tl][seg*8]   = *(const float4*)src;
      *(float4*)&BCS[tl][seg*8+4] = *(const float4*)(src+4);
    }
    // B2: stage dt (softplus of 16-dot), dt*xi, (xi,z); thread = (cs, 4 t's)
    #pragma unroll
    for (int k=0;k<4;k++){
      int tl = (tid>>5) + k*8;
      int st = s0 + tl;
      int t = dir ? (L_SEQ-1-st) : st;
      size_t row = bL + t;
      const float4* dp = (const float4*)&dtp[row*16];
      float4 a0 = dp[0], a1 = dp[1], a2 = dp[2], a3 = dp[3];
      float s = dtbv;
      s = fmaf(a0.x,w0.x, fmaf(a0.y,w0.y, fmaf(a0.z,w0.z, fmaf(a0.w,w0.w, s))));
      s = fmaf(a1.x,w1.x, fmaf(a1.y,w1.y, fmaf(a1.z,w1.z, fmaf(a1.w,w1.w, s))));
      s = fmaf(a2.x,w2.x, fmaf(a2.y,w2.y, fmaf(a2.z,w2.z, fmaf(a2.w,w2.w, s))));
      s = fmaf(a3.x,w3.x, fmaf(a3.y,w3.y, fmaf(a3.z,w3.z, fmaf(a3.w,w3.w, s))));
      float dtv = fmaxf(s,0.f) + __logf(1.f + __expf(-fabsf(s)));
      float xiv = bf2f(xhp[row*DI + d0 + cs]) + bf2f(xlp[row*DI + d0 + cs]);
      float zv  = zp[row*1024 + DI + d0 + cs];
      DTDX[cs][tl] = make_float2(dtv, dtv * xiv);
      XZt[cs][tl]  = make_float2(xiv, zv);
    }
    __syncthreads();
    // inner: 32 steps as 8 groups of 4, 2-deep register double-buffer
    LDGRP(p, 0)
    LDGRP(q, 4)
    CMPGRP(p, 0)   LDGRP(p, 8)
    CMPGRP(q, 4)   LDGRP(q, 12)
    CMPGRP(p, 8)   LDGRP(p, 16)
    CMPGRP(q, 12)  LDGRP(q, 20)
    CMPGRP(p, 16)  LDGRP(p, 24)
    CMPGRP(q, 20)  LDGRP(q, 28)
    CMPGRP(p, 24)
    CMPGRP(q, 28)
    __syncthreads();
  }
  // final E (chunk 15)
  #pragma unroll
  for (int k=0;k<4;k++){
    int e = tid + k*256;
    int tl = e>>5, cc = e&31;
    int st = 480 + tl;
    int t = dir ? (L_SEQ-1-st) : st;
    float v = YOT[cc][tl];
    ushort_t hh = f2bf(v);
    yoh[(bL + t)*1024 + d0 + cc] = hh;
    yol[(bL + t)*1024 + d0 + cc] = f2bf(v - bf2f(hh));
  }
#undef LDGRP
#undef STEP
#undef CMPGRP
}

// ---------------- gate + fuse -> bf16 planes of fused ----------------
__global__ __launch_bounds__(256) void fuse_kernel(const float* __restrict__ gpre,
   const float* __restrict__ gb, const float* __restrict__ ffr,
   ushort_t* __restrict__ fush, ushort_t* __restrict__ fusl)
{
  int idx = blockIdx.x*256 + threadIdx.x;
  int r = idx >> 8, c = idx & (DM-1);
  size_t ro = (size_t)r*2*DM;
  float ffv = ffr[ro + c];
  float frv = ffr[ro + DM + c];
  float g = 1.f/(1.f+__expf(-(gpre[idx] + gb[c])));
  float v = g*ffv + (1.f-g)*frv;
  ushort_t h = f2bf(v);
  fush[idx] = h;
  fusl[idx] = f2bf(v - bf2f(h));
}

extern "C" void kernel_launch(void* const* d_in, const int* in_sizes, int n_in,
                              void* d_out, int out_size, void* d_ws, size_t ws_size,
                              hipStream_t stream)
{
  (void)in_sizes; (void)n_in; (void)out_size; (void)ws_size;
  const float* x    = (const float*)d_in[0];
  const float* ln_g = (const float*)d_in[1];
  const float* ln_b = (const float*)d_in[2];
  const float* Win[2]  = {(const float*)d_in[3],  (const float*)d_in[12]};
  const float* convw[2]= {(const float*)d_in[4],  (const float*)d_in[13]};
  const float* convb[2]= {(const float*)d_in[5],  (const float*)d_in[14]};
  const float* Wx[2]   = {(const float*)d_in[6],  (const float*)d_in[15]};
  const float* Wdt[2]  = {(const float*)d_in[7],  (const float*)d_in[16]};
  const float* dtb[2]  = {(const float*)d_in[8],  (const float*)d_in[17]};
  const float* Alog[2] = {(const float*)d_in[9],  (const float*)d_in[18]};
  const float* Dpp[2]  = {(const float*)d_in[10], (const float*)d_in[19]};
  const float* Wout[2] = {(const float*)d_in[11], (const float*)d_in[20]};
  const float* gate_W = (const float*)d_in[21];
  const float* gate_b = (const float*)d_in[22];
  const float* op_W   = (const float*)d_in[23];
  const float* op_b   = (const float*)d_in[24];
  float* out = (float*)d_out;

  char* wsb = (char*)d_ws;
  size_t off = 0;
  auto allocB = [&](size_t bytes)->char*{
    char* p = wsb + off; off += (bytes + 255) & ~size_t(255); return p; };
  const size_t R = R_ROWS;

  // persistent region
  float* xzb  = (float*)allocB(2*R*1024*4);        // [m][R][1024]
  float* dtIn = (float*)allocB(2*2*R*16*4);        // [m][dir R][16]
  float* bc4  = (float*)allocB(2*2*R*64*4);        // [m][dir R][64]
  ushort_t* xnh = (ushort_t*)allocB(R*DM*2);
  ushort_t* xnl = (ushort_t*)allocB(R*DM*2);
  ushort_t* yhp = (ushort_t*)allocB(2*R*1024*2);   // [dir][R][1024], col m*512
  ushort_t* ylp = (ushort_t*)allocB(2*R*1024*2);
  // weight planes
  ushort_t* WiH[2] = {(ushort_t*)allocB(262144*2), (ushort_t*)allocB(262144*2)};
  ushort_t* WiL[2] = {(ushort_t*)allocB(262144*2), (ushort_t*)allocB(262144*2)};
  ushort_t* WxH[2] = {(ushort_t*)allocB(40960*2),  (ushort_t*)allocB(40960*2)};
  ushort_t* WxL[2] = {(ushort_t*)allocB(40960*2),  (ushort_t*)allocB(40960*2)};
  ushort_t* WoH = (ushort_t*)allocB(262144*2);
  ushort_t* WoL = (ushort_t*)allocB(262144*2);
  ushort_t* gH  = (ushort_t*)allocB(131072*2);
  ushort_t* gL  = (ushort_t*)allocB(131072*2);
  ushort_t* oH  = (ushort_t*)allocB(65536*2);
  ushort_t* oL  = (ushort_t*)allocB(65536*2);

  // union region: phase1 = xih/xil (live through scan); phase2 = post-scan buffers
  size_t uo = off;
  ushort_t* xih = (ushort_t*)allocB(2*2*R*DI*2);   // [m][dir R][512]
  ushort_t* xil = (ushort_t*)allocB(2*2*R*DI*2);
  // phase2 overlays (written only after scan completes)
  char* p2 = wsb + uo;
  float* ffr  = (float*)p2;              p2 += (size_t)R*2*DM*4;
  float* gpre = (float*)p2;              p2 += (size_t)R*DM*4;
  ushort_t* ffh = (ushort_t*)p2;         p2 += (size_t)R*2*DM*2;
  ushort_t* ffl = (ushort_t*)p2;         p2 += (size_t)R*2*DM*2;
  ushort_t* fsh = (ushort_t*)p2;         p2 += (size_t)R*DM*2;
  ushort_t* fsl = (ushort_t*)p2;         p2 += (size_t)R*DM*2;

  prep_weights<<<4160, 256, 0, stream>>>(Win[0], Win[1], Wx[0], Wx[1],
      Wout[0], Wout[1], gate_W, op_W,
      WiH[0], WiL[0], WiH[1], WiL[1], WxH[0], WxL[0], WxH[1], WxL[1],
      WoH, WoL, gH, gL, oH, oL);

  ln_kernel<<<R/4, 256, 0, stream>>>(x, ln_g, ln_b, xnh, xnl);

  for (int m=0; m<2; ++m){
    float* xzm = xzb + (size_t)m*R*1024;
    ushort_t* xihm = xih + (size_t)m*2*R*DI;
    ushort_t* xilm = xil + (size_t)m*2*R*DI;
    // xz = xn @ Win^T   [4096,256] x [1024,256]^T
    gemm_mfma<128,0><<<dim3(8, 32, 1), 256, 0, stream>>>(
        xnh, xnl, 0, WiH[m], WiL[m], DM, 1024, xzm, 1024, 0,
        nullptr, nullptr, 0, nullptr, nullptr);
    if (m==0) conv_kernel<4><<<2048,256,0,stream>>>(xzm, convw[m], convb[m], xihm, xilm);
    else      conv_kernel<8><<<2048,256,0,stream>>>(xzm, convw[m], convb[m], xihm, xilm);
    // x_dbl = xi @ Wx^T -> dtIn + bc4   [8192,512] x [80,512]^T
    gemm_mfma<64,4><<<dim3(1, 128, 1), 256, 0, stream>>>(
        xihm, xilm, 0, WxH[m], WxL[m], DI, 80, dtIn + (size_t)m*2*R*16, 16, 0,
        nullptr, nullptr, 0, nullptr, bc4 + (size_t)m*2*R*64);
  }
  // ONE merged scan: 512 blocks (XCD-local slices)
  scan_kernel<<<512, 256, 0, stream>>>(dtIn, bc4, xih, xil, xzb,
      Wdt[0], Wdt[1], dtb[0], dtb[1], Alog[0], Alog[1], Dpp[0], Dpp[1],
      yhp, ylp);
  // f_dir = y[dir] @ [Wout0;Wout1]^T  (K=1024), z=dir -> ffr cols dir*256..
  gemm_mfma<128,2><<<dim3(2, 32, 2), 256, 0, stream>>>(
      yhp, ylp, (long)R*1024, WoH, WoL, 1024, 256, ffr, 2*DM, DM,
      ffh, ffl, 2*DM, nullptr, nullptr);
  // gate pre-activation: ffr @ gate_W^T  [4096,512] x [256,512]^T
  gemm_mfma<64,0><<<dim3(2, 64, 1), 256, 0, stream>>>(
      ffh, ffl, 0, gH, gL, 2*DM, DM, gpre, DM, 0,
      nullptr, nullptr, 0, nullptr, nullptr);
  fuse_kernel<<<R*DM/256, 256, 0, stream>>>(gpre, gate_b, ffr, fsh, fsl);
  // out = fused @ op_W^T + op_b
  gemm_mfma<64,1><<<dim3(2, 64, 1), 256, 0, stream>>>(
      fsh, fsl, 0, oH, oL, DM, DM, out, DM, 0,
      nullptr, nullptr, 0, op_b, nullptr);
}